// Round 14
// baseline (851.250 us; speedup 1.0000x reference)
//
#include <hip/hip_runtime.h>
#include <math.h>

#define FEAT 128
#define NRBF 20
#define NCONV 3
#define PI_F 3.14159265358979323846f

typedef __attribute__((ext_vector_type(8))) short short8;
typedef __attribute__((ext_vector_type(4))) float floatx4;
typedef unsigned short ushort_t;

__device__ inline float b2f(unsigned short u) {
    union { unsigned int i; float f; } c; c.i = ((unsigned int)u) << 16; return c.f;
}
__device__ inline unsigned short f2b(float x) {
    union { float f; unsigned int i; } c; c.f = x;
    unsigned int u = c.i;
    return (unsigned short)((u + 0x7fffu + ((u >> 16) & 1u)) >> 16);
}

// ---------------------------------------------------------------------------
// Fused 2-layer MLP (BM=64, 4 waves x 64x32 slice, LDS 64 KB -> 2 blocks/CU).
// R14: exact revert to the R11 build (best measured, 751.8 us). W staged in
// LDS with the proven 2-barrier k-step lifecycle; R12's W-direct variant
// measured -9 us (L2 latency on the MFMA issue path outweighed the saved
// barrier drains).
// MODE 0: phi standalone:  s -> phi_b (bf16 hi), reads A from HBM.
// MODE 1: gate + update (final layer).
// MODE 2: gate + update + CHAINED next-layer phi-MLP.
// Gate input K>=128 reads precomputed nrm[m][128]; epilogue reads ONE uvd
// float4 {u0,u1,u2,dot}. Values identical to update_sv -> bitwise output.
// ---------------------------------------------------------------------------
template<int MODE>
__global__ __launch_bounds__(256, 2) void mlp_fused_kernel(
    const float* __restrict__ s, const float* __restrict__ nrm,
    const ushort_t* __restrict__ W1h, const ushort_t* __restrict__ W1l,
    const float* __restrict__ b1,
    const ushort_t* __restrict__ W2h, const ushort_t* __restrict__ W2l,
    const float* __restrict__ b2,
    ushort_t* __restrict__ out_b,
    const float4* __restrict__ uvd,    // MODE>=1: {u0,u1,u2,dot} per (m,g)
    float* s_out, float* vbuf,         // MODE>=1: s (rw), v (rw, planar 3xSP)
    float* outv,                       // MODE 1: interleaved v out
    const ushort_t* __restrict__ pW1h, const ushort_t* __restrict__ pW1l,
    const float* __restrict__ pb1,     // MODE 2: next-layer phi weights
    const ushort_t* __restrict__ pW2h, const ushort_t* __restrict__ pW2l,
    const float* __restrict__ pb2,
    ushort_t* __restrict__ pout,       // MODE 2: phi_b out
    int M, int K1, int SP)
{
    __shared__ __align__(16) ushort_t Ah[64 * 40];
    __shared__ __align__(16) ushort_t Al[64 * 40];
    __shared__ __align__(16) ushort_t Wh[128 * 40];
    __shared__ __align__(16) ushort_t Wl[128 * 40];
    __shared__ __align__(16) ushort_t Hh[64 * 136];
    __shared__ __align__(16) ushort_t Hl[64 * 136];

    const int t    = threadIdx.x;
    const int m0   = blockIdx.x * 64;
    const int wv   = t >> 6;
    const int lane = t & 63;
    const int wn   = wv * 32;         // wave's 32-col slice
    const int lr   = lane & 15;
    const int lk   = (lane >> 4) * 8;
    const int quad = lane >> 4;
    const int arow = t >> 3;          // 0..31, 2 passes of 32 rows
    const int acol = (t & 7) * 4;     // fp32 x4
    const int wrow = t >> 2;          // 0..63, 2 passes of 64 rows
    const int wcol = (t & 3) * 8;     // ushort x8

    floatx4 acc[4][2] = {};

    // ---- stage 1: h = silu(A1 @ W1^T + b1) ----
    for (int k0 = 0; k0 < K1; k0 += 32) {
        #pragma unroll
        for (int h = 0; h < 2; ++h) {
            int r = arow + h * 32;
            int m = m0 + r; if (m >= M) m = M - 1;   // clamp tail (in-block)
            float xs[4];
            if (k0 < 128) {
                float4 av = *(const float4*)(s + (long)m * 128 + k0 + acol);
                xs[0] = av.x; xs[1] = av.y; xs[2] = av.z; xs[3] = av.w;
            } else {
                float4 av = *(const float4*)(nrm + (long)m * 128 + (k0 - 128) + acol);
                xs[0] = av.x; xs[1] = av.y; xs[2] = av.z; xs[3] = av.w;
            }
            unsigned short hh[4], ll[4];
            #pragma unroll
            for (int q = 0; q < 4; ++q) {
                hh[q] = f2b(xs[q]);
                ll[q] = f2b(xs[q] - b2f(hh[q]));
            }
            *(ushort4*)(&Ah[r * 40 + acol]) = make_ushort4(hh[0], hh[1], hh[2], hh[3]);
            *(ushort4*)(&Al[r * 40 + acol]) = make_ushort4(ll[0], ll[1], ll[2], ll[3]);
        }
        #pragma unroll
        for (int h = 0; h < 2; ++h) {
            int r = wrow + h * 64;
            *(uint4*)(&Wh[r * 40 + wcol]) =
                *(const uint4*)(W1h + (long)r * K1 + k0 + wcol);
            *(uint4*)(&Wl[r * 40 + wcol]) =
                *(const uint4*)(W1l + (long)r * K1 + k0 + wcol);
        }
        __syncthreads();
        short8 af[4], alf[4], wf[2], wlf[2];
        #pragma unroll
        for (int i = 0; i < 4; ++i) {
            af[i]  = *(const short8*)(&Ah[(i * 16 + lr) * 40 + lk]);
            alf[i] = *(const short8*)(&Al[(i * 16 + lr) * 40 + lk]);
        }
        #pragma unroll
        for (int j = 0; j < 2; ++j) {
            wf[j]  = *(const short8*)(&Wh[(wn + j * 16 + lr) * 40 + lk]);
            wlf[j] = *(const short8*)(&Wl[(wn + j * 16 + lr) * 40 + lk]);
        }
        #pragma unroll
        for (int i = 0; i < 4; ++i)
            #pragma unroll
            for (int j = 0; j < 2; ++j) {
                acc[i][j] = __builtin_amdgcn_mfma_f32_16x16x32_bf16(
                    af[i], wf[j], acc[i][j], 0, 0, 0);
                acc[i][j] = __builtin_amdgcn_mfma_f32_16x16x32_bf16(
                    af[i], wlf[j], acc[i][j], 0, 0, 0);
                acc[i][j] = __builtin_amdgcn_mfma_f32_16x16x32_bf16(
                    alf[i], wf[j], acc[i][j], 0, 0, 0);
            }
        __syncthreads();
    }

    // stage-1 epilogue -> h in LDS (hi/lo), C/D layout col=lane&15, row=quad*4+r
    #pragma unroll
    for (int i = 0; i < 4; ++i)
        #pragma unroll
        for (int r = 0; r < 4; ++r) {
            int mrow = i * 16 + quad * 4 + r;
            #pragma unroll
            for (int j = 0; j < 2; ++j) {
                int kcol = wn + j * 16 + lr;
                float x = acc[i][j][r] + b1[kcol];
                x *= 1.f / (1.f + __expf(-x));
                unsigned short hh = f2b(x);
                Hh[mrow * 136 + kcol] = hh;
                Hl[mrow * 136 + kcol] = f2b(x - b2f(hh));
            }
        }

    // ---- stage 2: 3 n-tiles of 128; MODE>=1 keeps all accumulators ----
    floatx4 accS[3][4][2];
    #pragma unroll
    for (int nt = 0; nt < 3; ++nt) {
        floatx4 a2c[4][2] = {};
        for (int k0 = 0; k0 < 128; k0 += 32) {
            __syncthreads();   // guard Wh/Wl overwrite (and H writes on 1st pass)
            #pragma unroll
            for (int h = 0; h < 2; ++h) {
                int r = wrow + h * 64;
                long wo = (long)(nt * 128 + r) * 128;
                *(uint4*)(&Wh[r * 40 + wcol]) = *(const uint4*)(W2h + wo + k0 + wcol);
                *(uint4*)(&Wl[r * 40 + wcol]) = *(const uint4*)(W2l + wo + k0 + wcol);
            }
            __syncthreads();
            short8 af[4], alf[4], wf[2], wlf[2];
            #pragma unroll
            for (int i = 0; i < 4; ++i) {
                af[i]  = *(const short8*)(&Hh[(i * 16 + lr) * 136 + k0 + lk]);
                alf[i] = *(const short8*)(&Hl[(i * 16 + lr) * 136 + k0 + lk]);
            }
            #pragma unroll
            for (int j = 0; j < 2; ++j) {
                wf[j]  = *(const short8*)(&Wh[(wn + j * 16 + lr) * 40 + lk]);
                wlf[j] = *(const short8*)(&Wl[(wn + j * 16 + lr) * 40 + lk]);
            }
            #pragma unroll
            for (int i = 0; i < 4; ++i)
                #pragma unroll
                for (int j = 0; j < 2; ++j) {
                    a2c[i][j] = __builtin_amdgcn_mfma_f32_16x16x32_bf16(
                        af[i], wf[j], a2c[i][j], 0, 0, 0);
                    a2c[i][j] = __builtin_amdgcn_mfma_f32_16x16x32_bf16(
                        af[i], wlf[j], a2c[i][j], 0, 0, 0);
                    a2c[i][j] = __builtin_amdgcn_mfma_f32_16x16x32_bf16(
                        alf[i], wf[j], a2c[i][j], 0, 0, 0);
                }
        }
        if (MODE >= 1) {
            #pragma unroll
            for (int i = 0; i < 4; ++i)
                #pragma unroll
                for (int j = 0; j < 2; ++j)
                    accS[nt][i][j] = a2c[i][j];
        } else {
            #pragma unroll
            for (int i = 0; i < 4; ++i)
                #pragma unroll
                for (int r = 0; r < 4; ++r) {
                    int m = m0 + i * 16 + quad * 4 + r;
                    if (m >= M) continue;
                    #pragma unroll
                    for (int j = 0; j < 2; ++j) {
                        int n = nt * 128 + wn + j * 16 + lr;
                        out_b[(long)m * 384 + n] = f2b(a2c[i][j][r] + b2[n]);
                    }
                }
        }
    }

    // ---- fused update epilogue (gate modes): update_sv arithmetic in-place ----
    if (MODE >= 1) {
        if (MODE == 2) __syncthreads();   // all waves done reading H (stage 2)
        #pragma unroll
        for (int i = 0; i < 4; ++i)
            #pragma unroll
            for (int r = 0; r < 4; ++r) {
                int m = m0 + i * 16 + quad * 4 + r;
                if (m >= M) continue;
                #pragma unroll
                for (int j = 0; j < 2; ++j) {
                    int g = wn + j * 16 + lr;
                    long idx = (long)m * 128 + g;
                    float a0 = accS[0][i][j][r] + b2[g];
                    float a1 = accS[1][i][j][r] + b2[128 + g];
                    float a2 = accS[2][i][j][r] + b2[256 + g];
                    float4 ud = uvd[idx];            // {u0,u1,u2,dot}
                    float sn = s[idx] + ud.w * a1 + a2;
                    s_out[idx] = sn;
                    if (MODE == 2) {
                        int mrow = i * 16 + quad * 4 + r;
                        unsigned short sh = f2b(sn);
                        Hh[mrow * 136 + g] = sh;           // s_new -> LDS for
                        Hl[mrow * 136 + g] = f2b(sn - b2f(sh));  // chained phi
                    }
                    float x0 = vbuf[idx]          + ud.x * a0;
                    float x1 = vbuf[SP + idx]     + ud.y * a0;
                    float x2 = vbuf[2 * SP + idx] + ud.z * a0;
                    if (MODE == 1 && outv) {
                        outv[idx * 3 + 0] = x0;
                        outv[idx * 3 + 1] = x1;
                        outv[idx * 3 + 2] = x2;
                    } else {
                        vbuf[idx]          = x0;
                        vbuf[SP + idx]     = x1;
                        vbuf[2 * SP + idx] = x2;
                    }
                }
            }
    }

    // ---- MODE 2: chained next-layer phi-MLP (A = s_new from LDS) ----
    if (MODE == 2) {
        __syncthreads();   // s_new visible in Hh/Hl
        floatx4 pacc[4][2] = {};
        for (int k0 = 0; k0 < 128; k0 += 32) {
            __syncthreads();                  // guard Wh/Wl overwrite
            #pragma unroll
            for (int h = 0; h < 2; ++h) {
                int r = wrow + h * 64;
                *(uint4*)(&Wh[r * 40 + wcol]) =
                    *(const uint4*)(pW1h + (long)r * 128 + k0 + wcol);
                *(uint4*)(&Wl[r * 40 + wcol]) =
                    *(const uint4*)(pW1l + (long)r * 128 + k0 + wcol);
            }
            __syncthreads();
            short8 af[4], alf[4], wf[2], wlf[2];
            #pragma unroll
            for (int i = 0; i < 4; ++i) {
                af[i]  = *(const short8*)(&Hh[(i * 16 + lr) * 136 + k0 + lk]);
                alf[i] = *(const short8*)(&Hl[(i * 16 + lr) * 136 + k0 + lk]);
            }
            #pragma unroll
            for (int j = 0; j < 2; ++j) {
                wf[j]  = *(const short8*)(&Wh[(wn + j * 16 + lr) * 40 + lk]);
                wlf[j] = *(const short8*)(&Wl[(wn + j * 16 + lr) * 40 + lk]);
            }
            #pragma unroll
            for (int i = 0; i < 4; ++i)
                #pragma unroll
                for (int j = 0; j < 2; ++j) {
                    pacc[i][j] = __builtin_amdgcn_mfma_f32_16x16x32_bf16(
                        af[i], wf[j], pacc[i][j], 0, 0, 0);
                    pacc[i][j] = __builtin_amdgcn_mfma_f32_16x16x32_bf16(
                        af[i], wlf[j], pacc[i][j], 0, 0, 0);
                    pacc[i][j] = __builtin_amdgcn_mfma_f32_16x16x32_bf16(
                        alf[i], wf[j], pacc[i][j], 0, 0, 0);
                }
        }
        __syncthreads();   // all waves done reading s_new; h may overwrite
        #pragma unroll
        for (int i = 0; i < 4; ++i)
            #pragma unroll
            for (int r = 0; r < 4; ++r) {
                int mrow = i * 16 + quad * 4 + r;
                #pragma unroll
                for (int j = 0; j < 2; ++j) {
                    int kcol = wn + j * 16 + lr;
                    float x = pacc[i][j][r] + pb1[kcol];
                    x *= 1.f / (1.f + __expf(-x));
                    unsigned short hh = f2b(x);
                    Hh[mrow * 136 + kcol] = hh;
                    Hl[mrow * 136 + kcol] = f2b(x - b2f(hh));
                }
            }
        for (int nt = 0; nt < 3; ++nt) {
            floatx4 c2[4][2] = {};
            for (int k0 = 0; k0 < 128; k0 += 32) {
                __syncthreads();   // covers h-write visibility + Wh overwrite
                #pragma unroll
                for (int h = 0; h < 2; ++h) {
                    int r = wrow + h * 64;
                    long wo = (long)(nt * 128 + r) * 128;
                    *(uint4*)(&Wh[r * 40 + wcol]) =
                        *(const uint4*)(pW2h + wo + k0 + wcol);
                    *(uint4*)(&Wl[r * 40 + wcol]) =
                        *(const uint4*)(pW2l + wo + k0 + wcol);
                }
                __syncthreads();
                short8 af[4], alf[4], wf[2], wlf[2];
                #pragma unroll
                for (int i = 0; i < 4; ++i) {
                    af[i]  = *(const short8*)(&Hh[(i * 16 + lr) * 136 + k0 + lk]);
                    alf[i] = *(const short8*)(&Hl[(i * 16 + lr) * 136 + k0 + lk]);
                }
                #pragma unroll
                for (int j = 0; j < 2; ++j) {
                    wf[j]  = *(const short8*)(&Wh[(wn + j * 16 + lr) * 40 + lk]);
                    wlf[j] = *(const short8*)(&Wl[(wn + j * 16 + lr) * 40 + lk]);
                }
                #pragma unroll
                for (int i = 0; i < 4; ++i)
                    #pragma unroll
                    for (int j = 0; j < 2; ++j) {
                        c2[i][j] = __builtin_amdgcn_mfma_f32_16x16x32_bf16(
                            af[i], wf[j], c2[i][j], 0, 0, 0);
                        c2[i][j] = __builtin_amdgcn_mfma_f32_16x16x32_bf16(
                            af[i], wlf[j], c2[i][j], 0, 0, 0);
                        c2[i][j] = __builtin_amdgcn_mfma_f32_16x16x32_bf16(
                            alf[i], wf[j], c2[i][j], 0, 0, 0);
                    }
            }
            #pragma unroll
            for (int i = 0; i < 4; ++i)
                #pragma unroll
                for (int r = 0; r < 4; ++r) {
                    int m = m0 + i * 16 + quad * 4 + r;
                    if (m >= M) continue;
                    #pragma unroll
                    for (int j = 0; j < 2; ++j) {
                        int n = nt * 128 + wn + j * 16 + lr;
                        pout[(long)m * 384 + n] = f2b(c2[i][j][r] + pb2[n]);
                    }
                }
        }
    }
}

// ---------------------------------------------------------------------------
// Fused U+V GEMM over vn in [node][4comp][feat] layout (comp3 = zero).
// Rows 4n..4n+3 of A are the 4 comps of node n; MFMA C/D layout gives each
// thread 4 CONSECUTIVE rows in acc[.][.][0..3] -> all comps of one node.
// Epilogue emits uvd = {u0,u1,u2,dot(u,v)} (float4) and nrm = |v| directly,
// eliminating the u_v/v_v round-trip (~92 MB/layer). Values are the same
// fp32 accumulators previously stored+reloaded -> bitwise-identical output.
// ---------------------------------------------------------------------------
__global__ __launch_bounds__(256, 2) void gemm_uv_kernel(
    const ushort_t* __restrict__ Ahg, const ushort_t* __restrict__ Alg,
    const ushort_t* __restrict__ Uh, const ushort_t* __restrict__ Ul,
    const ushort_t* __restrict__ Vh, const ushort_t* __restrict__ Vl,
    float4* __restrict__ uvd, float* __restrict__ nrm,
    int Mr)                                     // Mr = 4N rows, K = 128
{
    __shared__ __align__(16) ushort_t Ah[128 * 40];
    __shared__ __align__(16) ushort_t Al[128 * 40];
    __shared__ __align__(16) ushort_t WUh[128 * 40];
    __shared__ __align__(16) ushort_t WUl[128 * 40];
    __shared__ __align__(16) ushort_t WVh[128 * 40];
    __shared__ __align__(16) ushort_t WVl[128 * 40];
    const int t    = threadIdx.x;
    const int m0   = blockIdx.x * 128;
    const int wv   = t >> 6;
    const int lane = t & 63;
    const int wm   = (wv >> 1) * 64;
    const int wn   = (wv & 1) * 64;
    const int lr   = lane & 15;
    const int lk   = (lane >> 4) * 8;
    const int quad = lane >> 4;
    const int srow = t >> 2;
    const int scol = (t & 3) * 8;

    floatx4 aU[4][4] = {};
    floatx4 aV[4][4] = {};

    for (int k0 = 0; k0 < 128; k0 += 32) {
        #pragma unroll
        for (int h = 0; h < 2; ++h) {
            int r = srow + h * 64;
            int m = m0 + r; if (m >= Mr) m = Mr - 1;
            *(uint4*)(&Ah[r * 40 + scol])  = *(const uint4*)(Ahg + (long)m * 128 + k0 + scol);
            *(uint4*)(&Al[r * 40 + scol])  = *(const uint4*)(Alg + (long)m * 128 + k0 + scol);
            *(uint4*)(&WUh[r * 40 + scol]) = *(const uint4*)(Uh + (long)r * 128 + k0 + scol);
            *(uint4*)(&WUl[r * 40 + scol]) = *(const uint4*)(Ul + (long)r * 128 + k0 + scol);
            *(uint4*)(&WVh[r * 40 + scol]) = *(const uint4*)(Vh + (long)r * 128 + k0 + scol);
            *(uint4*)(&WVl[r * 40 + scol]) = *(const uint4*)(Vl + (long)r * 128 + k0 + scol);
        }
        __syncthreads();
        short8 ah[4], al[4];
        #pragma unroll
        for (int i = 0; i < 4; ++i) {
            ah[i] = *(const short8*)(&Ah[(wm + i * 16 + lr) * 40 + lk]);
            al[i] = *(const short8*)(&Al[(wm + i * 16 + lr) * 40 + lk]);
        }
        #pragma unroll
        for (int j = 0; j < 4; ++j) {
            short8 wuh = *(const short8*)(&WUh[(wn + j * 16 + lr) * 40 + lk]);
            short8 wul = *(const short8*)(&WUl[(wn + j * 16 + lr) * 40 + lk]);
            short8 wvh = *(const short8*)(&WVh[(wn + j * 16 + lr) * 40 + lk]);
            short8 wvl = *(const short8*)(&WVl[(wn + j * 16 + lr) * 40 + lk]);
            #pragma unroll
            for (int i = 0; i < 4; ++i) {
                aU[i][j] = __builtin_amdgcn_mfma_f32_16x16x32_bf16(
                    ah[i], wuh, aU[i][j], 0, 0, 0);
                aU[i][j] = __builtin_amdgcn_mfma_f32_16x16x32_bf16(
                    ah[i], wul, aU[i][j], 0, 0, 0);
                aU[i][j] = __builtin_amdgcn_mfma_f32_16x16x32_bf16(
                    al[i], wuh, aU[i][j], 0, 0, 0);
                aV[i][j] = __builtin_amdgcn_mfma_f32_16x16x32_bf16(
                    ah[i], wvh, aV[i][j], 0, 0, 0);
                aV[i][j] = __builtin_amdgcn_mfma_f32_16x16x32_bf16(
                    ah[i], wvl, aV[i][j], 0, 0, 0);
                aV[i][j] = __builtin_amdgcn_mfma_f32_16x16x32_bf16(
                    al[i], wvh, aV[i][j], 0, 0, 0);
            }
        }
        __syncthreads();
    }

    #pragma unroll
    for (int i = 0; i < 4; ++i) {
        int mbase = m0 + wm + i * 16 + quad * 4;   // multiple of 4
        if (mbase >= Mr) continue;
        int node = mbase >> 2;
        #pragma unroll
        for (int j = 0; j < 4; ++j) {
            int n = wn + j * 16 + lr;
            float u0 = aU[i][j][0], u1 = aU[i][j][1], u2 = aU[i][j][2];
            float w0 = aV[i][j][0], w1 = aV[i][j][1], w2 = aV[i][j][2];
            float dot = u0 * w0 + u1 * w1 + u2 * w2;
            uvd[(long)node * 128 + n] = make_float4(u0, u1, u2, dot);
            nrm[(long)node * 128 + n] = sqrtf(w0 * w0 + w1 * w1 + w2 * w2);
        }
    }
}

// ---------------------------------------------------------------------------
__global__ __launch_bounds__(256) void split_kernel(
    const float* __restrict__ src, ushort_t* __restrict__ hi,
    ushort_t* __restrict__ lo, int n)
{
    int i = blockIdx.x * blockDim.x + threadIdx.x;
    if (i >= n) return;
    float x = src[i];
    unsigned short h = f2b(x);
    hi[i] = h;
    lo[i] = f2b(x - b2f(h));
}

// ---------------------------------------------------------------------------
// CSR build
// ---------------------------------------------------------------------------
__global__ __launch_bounds__(256) void hist_kernel(
    const int* __restrict__ nbr, int* __restrict__ deg, int Ed)
{
    int e = blockIdx.x * blockDim.x + threadIdx.x;
    if (e >= Ed) return;
    int E = Ed >> 1;
    int i = (e < E) ? nbr[2 * e] : nbr[2 * (e - E) + 1];
    atomicAdd(&deg[i], 1);
}

__device__ inline int wave_incl_scan(int x, int lane)
{
    #pragma unroll
    for (int s = 1; s < 64; s <<= 1) {
        int y = __shfl_up(x, s, 64);
        if (lane >= s) x += y;
    }
    return x;
}

__global__ __launch_bounds__(1024) void scan_kernel(
    const int* __restrict__ deg, int* __restrict__ off,
    int* __restrict__ cursor, int N)
{
    __shared__ int wsum[16];
    __shared__ int carry_s;
    const int t = threadIdx.x;
    const int lane = t & 63;
    const int w = t >> 6;
    if (t == 0) { carry_s = 0; off[0] = 0; }
    __syncthreads();
    for (int base = 0; base < N; base += 1024) {
        int i = base + t;
        int x = (i < N) ? deg[i] : 0;
        int sc = wave_incl_scan(x, lane);
        if (lane == 63) wsum[w] = sc;
        __syncthreads();
        if (w == 0) {
            int v = (lane < 16) ? wsum[lane] : 0;
            int vs = wave_incl_scan(v, lane);
            if (lane < 16) wsum[lane] = vs;
        }
        __syncthreads();
        int waveoff = (w > 0) ? wsum[w - 1] : 0;
        int inc = sc + waveoff + carry_s;
        if (i < N) { off[i + 1] = inc; cursor[i] = inc - x; }
        __syncthreads();
        if (t == 1023) carry_s = inc;
        __syncthreads();
    }
}

__global__ __launch_bounds__(256) void scatter_geom_kernel(
    const int* __restrict__ nbr, const float* __restrict__ xyz,
    int* __restrict__ cursor, int* __restrict__ csr_j,
    float* __restrict__ csr_env, float* __restrict__ csr_unit,
    float* __restrict__ csr_rbfe, int Ed)
{
    int e = blockIdx.x * blockDim.x + threadIdx.x;
    if (e >= Ed) return;
    int E = Ed >> 1;
    int i, j;
    if (e < E) { i = nbr[2 * e];         j = nbr[2 * e + 1]; }
    else       { int u = e - E; i = nbr[2 * u + 1]; j = nbr[2 * u]; }

    int p = atomicAdd(&cursor[i], 1);
    csr_j[p] = j;

    float rx = xyz[3 * j + 0] - xyz[3 * i + 0];
    float ry = xyz[3 * j + 1] - xyz[3 * i + 1];
    float rz = xyz[3 * j + 2] - xyz[3 * i + 2];
    float d   = sqrtf(rx * rx + ry * ry + rz * rz);
    float inv = 1.f / d;
    csr_unit[3 * p + 0] = rx * inv;
    csr_unit[3 * p + 1] = ry * inv;
    csr_unit[3 * p + 2] = rz * inv;
    float ev = (d < 20.f) ? 0.5f * (__cosf(PI_F * d / 20.f) + 1.f) : 0.f;
    csr_env[p] = ev;
    float base = PI_F * d / 20.f;
    #pragma unroll
    for (int k = 0; k < NRBF; ++k)
        csr_rbfe[(long)p * NRBF + k] = ev * __sinf((float)(k + 1) * base) * inv;
}

// ---------------------------------------------------------------------------
// Edge aggregation — EXACT R0 inner loop, grid 2048 (proven optimum).
// vnh/vnl stores in [node][4comp][feat] layout (comp3 pre-zeroed once).
// ---------------------------------------------------------------------------
__global__ __launch_bounds__(128) void edge_aggr_kernel(
    const int* __restrict__ off, const int* __restrict__ csr_j,
    const float* __restrict__ csr_env, const float* __restrict__ csr_unit,
    const float* __restrict__ csr_rbfe,
    const ushort_t* __restrict__ phib, const float* __restrict__ vold,
    const float* __restrict__ distW, const float* __restrict__ distb,
    float* __restrict__ s, float* __restrict__ vnew,
    ushort_t* __restrict__ vnh, ushort_t* __restrict__ vnl, int N, int SP)
{
    const int f = threadIdx.x;
    float w0c[NRBF], w1c[NRBF], w2c[NRBF];
    const float b0 = distb[f];
    const float b1 = distb[128 + f];
    const float b2 = distb[256 + f];
    #pragma unroll
    for (int k = 0; k < NRBF; ++k) {
        w0c[k] = distW[(long)f * NRBF + k];
        w1c[k] = distW[(long)(128 + f) * NRBF + k];
        w2c[k] = distW[(long)(256 + f) * NRBF + k];
    }

    for (int node = blockIdx.x; node < N; node += gridDim.x) {
        const int p0 = off[node], p1 = off[node + 1];
        float ssum = 0.f, v0 = 0.f, v1 = 0.f, v2 = 0.f;
        for (int p = p0; p < p1; ++p) {
            int j = csr_j[p];
            float ev = csr_env[p];
            float ux = csr_unit[3 * p + 0];
            float uy = csr_unit[3 * p + 1];
            float uz = csr_unit[3 * p + 2];
            const float* rb = csr_rbfe + (long)p * NRBF;
            float w0 = ev * b0, w1 = ev * b1, w2 = ev * b2;
            #pragma unroll
            for (int k = 0; k < NRBF; ++k) {
                float r = rb[k];
                w0 += r * w0c[k];
                w1 += r * w1c[k];
                w2 += r * w2c[k];
            }
            long jb = (long)j * 384;
            float i0 = b2f(phib[jb + f])       * w0;
            float i1 = b2f(phib[jb + 128 + f]) * w1;
            float i2 = b2f(phib[jb + 256 + f]) * w2;
            long jv = (long)j * FEAT + f;
            ssum += i1;
            v0 += i2 * ux + i0 * vold[jv];
            v1 += i2 * uy + i0 * vold[SP + jv];
            v2 += i2 * uz + i0 * vold[2 * SP + jv];
        }
        long iv = (long)node * FEAT + f;
        s[iv] += ssum;
        float n0 = vold[iv]          + v0;
        float n1 = vold[SP + iv]     + v1;
        float n2 = vold[2 * SP + iv] + v2;
        vnew[iv]          = n0;
        vnew[SP + iv]     = n1;
        vnew[2 * SP + iv] = n2;
        unsigned short h0 = f2b(n0), h1 = f2b(n1), h2 = f2b(n2);
        long ib = (long)node * 512 + f;      // [node][4comp][feat] layout
        vnh[ib]       = h0;  vnl[ib]       = f2b(n0 - b2f(h0));
        vnh[ib + 128] = h1;  vnl[ib + 128] = f2b(n1 - b2f(h1));
        vnh[ib + 256] = h2;  vnl[ib + 256] = f2b(n2 - b2f(h2));
    }
}

// ---------------------------------------------------------------------------
// Elementwise kernels
// ---------------------------------------------------------------------------
__global__ __launch_bounds__(256) void init_s_kernel(
    const float* __restrict__ cg_s, float* __restrict__ s,
    float* __restrict__ vA, int nS, int nV)
{
    int idx = blockIdx.x * blockDim.x + threadIdx.x;
    if (idx < nS) s[idx] = cg_s[idx];
    if (idx < nV) vA[idx] = 0.f;
}

// ---------------------------------------------------------------------------
extern "C" void kernel_launch(void* const* d_in, const int* in_sizes, int n_in,
                              void* d_out, int out_size, void* d_ws, size_t ws_size,
                              hipStream_t stream)
{
    const float* xyz     = (const float*)d_in[0];
    const int*   nbr     = (const int*)  d_in[1];
    const float* cg_s    = (const float*)d_in[2];
    const float* msg_W1  = (const float*)d_in[3];
    const float* msg_b1  = (const float*)d_in[4];
    const float* msg_W2  = (const float*)d_in[5];
    const float* msg_b2  = (const float*)d_in[6];
    const float* dist_W  = (const float*)d_in[7];
    const float* dist_b  = (const float*)d_in[8];
    const float* upd_U   = (const float*)d_in[9];
    const float* upd_V   = (const float*)d_in[10];
    const float* upd_sW1 = (const float*)d_in[11];
    const float* upd_sb1 = (const float*)d_in[12];
    const float* upd_sW2 = (const float*)d_in[13];
    const float* upd_sb2 = (const float*)d_in[14];

    const int E  = in_sizes[1] / 2;
    const int Ed = 2 * E;
    const int N  = in_sizes[2] / FEAT;
    const int SP = N * FEAT;

    float* s    = (float*)d_out;
    float* outv = (float*)d_out + (long)SP;

    // workspace carve-up
    float* w = (float*)d_ws;
    size_t off_ = 0;
    auto alloc = [&](size_t nelem) {
        float* p = w + off_;
        off_ += (nelem + 255) & ~(size_t)255;
        return p;
    };
    auto allocb = [&](size_t nelem) {
        return (ushort_t*)alloc((nelem + 1) / 2);
    };
    int*   deg      = (int*)alloc((size_t)N);
    int*   off      = (int*)alloc((size_t)N + 1);
    int*   cursor   = (int*)alloc((size_t)N);
    int*   csr_j    = (int*)alloc((size_t)Ed);
    float* csr_env  = alloc((size_t)Ed);
    float* csr_unit = alloc((size_t)Ed * 3);
    float* csr_rbfe = alloc((size_t)Ed * NRBF);
    float* uvd      = alloc((size_t)4 * SP);   // {u0,u1,u2,dot} per (node,g)
    float* nrm      = alloc((size_t)SP);       // |v_v| per (node,g)
    float* vA       = alloc((size_t)3 * SP);
    float* vB       = alloc((size_t)3 * SP);
    ushort_t* phi_b = allocb((size_t)N * 384);
    ushort_t* vnh   = allocb((size_t)4 * SP);  // [node][4comp][feat], comp3=0
    ushort_t* vnl   = allocb((size_t)4 * SP);
    const int n1 = NCONV * FEAT * FEAT;
    const int n2 = NCONV * 3 * FEAT * FEAT;
    const int n3 = NCONV * FEAT * 2 * FEAT;
    ushort_t* w1h  = allocb((size_t)n1);
    ushort_t* w1l  = allocb((size_t)n1);
    ushort_t* w2h  = allocb((size_t)n2);
    ushort_t* w2l  = allocb((size_t)n2);
    ushort_t* uh   = allocb((size_t)n1);
    ushort_t* ul   = allocb((size_t)n1);
    ushort_t* vh   = allocb((size_t)n1);
    ushort_t* vl   = allocb((size_t)n1);
    ushort_t* sw1h = allocb((size_t)n3);
    ushort_t* sw1l = allocb((size_t)n3);
    ushort_t* sw2h = allocb((size_t)n2);
    ushort_t* sw2l = allocb((size_t)n2);
    (void)ws_size; (void)n_in; (void)out_size;

    // weight split (once per launch)
    split_kernel<<<(n1 + 255) / 256, 256, 0, stream>>>(msg_W1, w1h, w1l, n1);
    split_kernel<<<(n2 + 255) / 256, 256, 0, stream>>>(msg_W2, w2h, w2l, n2);
    split_kernel<<<(n1 + 255) / 256, 256, 0, stream>>>(upd_U, uh, ul, n1);
    split_kernel<<<(n1 + 255) / 256, 256, 0, stream>>>(upd_V, vh, vl, n1);
    split_kernel<<<(n3 + 255) / 256, 256, 0, stream>>>(upd_sW1, sw1h, sw1l, n3);
    split_kernel<<<(n2 + 255) / 256, 256, 0, stream>>>(upd_sW2, sw2h, sw2l, n2);

    // init s <- cg_s, vA <- 0; zero vnh/vnl once (comp3 stays 0 across layers)
    {
        int n = 3 * SP;
        init_s_kernel<<<(n + 255) / 256, 256, 0, stream>>>(cg_s, s, vA, SP, n);
        hipMemsetAsync(vnh, 0, (size_t)4 * SP * sizeof(ushort_t), stream);
        hipMemsetAsync(vnl, 0, (size_t)4 * SP * sizeof(ushort_t), stream);
    }

    // CSR build (once per launch)
    hipMemsetAsync(deg, 0, (size_t)N * sizeof(int), stream);
    hist_kernel<<<(Ed + 255) / 256, 256, 0, stream>>>(nbr, deg, Ed);
    scan_kernel<<<1, 1024, 0, stream>>>(deg, off, cursor, N);
    scatter_geom_kernel<<<(Ed + 255) / 256, 256, 0, stream>>>(
        nbr, xyz, cursor, csr_j, csr_env, csr_unit, csr_rbfe, Ed);

    float* vold = vA;
    float* vnew = vB;
    dim3 gM((N + 63) / 64, 1);
    dim3 gUV((4 * N + 127) / 128, 1);
    int edgeGrid = 2048;
    if (edgeGrid > N) edgeGrid = N;

    for (int l = 0; l < NCONV; ++l) {
        const float* b2  = msg_b2  + (long)l * 3 * FEAT;
        const float* dW  = dist_W  + (long)l * 3 * FEAT * NRBF;
        const float* db  = dist_b  + (long)l * 3 * FEAT;
        const float* sb1 = upd_sb1 + (long)l * FEAT;
        const float* sb2 = upd_sb2 + (long)l * 3 * FEAT;
        const long o1 = (long)l * FEAT * FEAT;
        const long o2 = (long)l * 3 * FEAT * FEAT;
        const long o3 = (long)l * FEAT * 2 * FEAT;

        // phi-MLP for layer 0 only; layers 1,2 get phi from the chained MODE 2
        if (l == 0) {
            const float* b1 = msg_b1;
            mlp_fused_kernel<0><<<gM, 256, 0, stream>>>(
                s, nullptr, w1h, w1l, b1, w2h, w2l, b2,
                phi_b, nullptr, nullptr, nullptr, nullptr,
                nullptr, nullptr, nullptr, nullptr, nullptr, nullptr, nullptr,
                N, FEAT, SP);
        }

        // atomic-free message aggregation (R0 loop, 2048 persistent blocks)
        edge_aggr_kernel<<<edgeGrid, 128, 0, stream>>>(
            off, csr_j, csr_env, csr_unit, csr_rbfe, phi_b, vold,
            dW, db, s, vnew, vnh, vnl, N, SP);

        // fused U+V GEMM -> uvd {u0,u1,u2,dot} + nrm
        gemm_uv_kernel<<<gUV, 256, 0, stream>>>(
            vnh, vnl, uh + o1, ul + o1, vh + o1, vl + o1,
            (float4*)uvd, nrm, 4 * N);

        if (l < NCONV - 1) {
            // gate-MLP + update + CHAINED phi-MLP of layer l+1
            const long o1n = (long)(l + 1) * FEAT * FEAT;
            const long o2n = (long)(l + 1) * 3 * FEAT * FEAT;
            const float* pb1 = msg_b1 + (long)(l + 1) * FEAT;
            const float* pb2 = msg_b2 + (long)(l + 1) * 3 * FEAT;
            mlp_fused_kernel<2><<<gM, 256, 0, stream>>>(
                s, nrm, sw1h + o3, sw1l + o3, sb1, sw2h + o2, sw2l + o2, sb2,
                nullptr, (const float4*)uvd, s, vnew, nullptr,
                w1h + o1n, w1l + o1n, pb1, w2h + o2n, w2l + o2n, pb2, phi_b,
                N, 2 * FEAT, SP);
        } else {
            // final gate-MLP + update; v written interleaved straight to output
            mlp_fused_kernel<1><<<gM, 256, 0, stream>>>(
                s, nrm, sw1h + o3, sw1l + o3, sb1, sw2h + o2, sw2l + o2, sb2,
                nullptr, (const float4*)uvd, s, vnew, outv,
                nullptr, nullptr, nullptr, nullptr, nullptr, nullptr, nullptr,
                N, 2 * FEAT, SP);
        }

        float* tmp = vold; vold = vnew; vnew = tmp;
    }
}

// Round 15
// 746.308 us; speedup vs baseline: 1.1406x; 1.1406x over previous
//
#include <hip/hip_runtime.h>
#include <math.h>

#define FEAT 128
#define NRBF 20
#define NCONV 3
#define PI_F 3.14159265358979323846f

typedef __attribute__((ext_vector_type(8))) short short8;
typedef __attribute__((ext_vector_type(4))) float floatx4;
typedef unsigned short ushort_t;

__device__ inline float b2f(unsigned short u) {
    union { unsigned int i; float f; } c; c.i = ((unsigned int)u) << 16; return c.f;
}
__device__ inline unsigned short f2b(float x) {
    union { float f; unsigned int i; } c; c.f = x;
    unsigned int u = c.i;
    return (unsigned short)((u + 0x7fffu + ((u >> 16) & 1u)) >> 16);
}

// ---------------------------------------------------------------------------
// Fused 2-layer MLP (BM=64, 4 waves x 64x32 slice, LDS 64 KB -> 2 blocks/CU).
// Best-verified build (R11: 751.8 us). W staged in LDS with the proven
// 2-barrier k-step lifecycle. R14 measured this same code at 851 us on a
// downclocked container (uniform 1.13x inflation); resubmitted unchanged.
// MODE 0: phi standalone:  s -> phi_b (bf16 hi), reads A from HBM.
// MODE 1: gate + update (final layer).
// MODE 2: gate + update + CHAINED next-layer phi-MLP.
// Gate input K>=128 reads precomputed nrm[m][128]; epilogue reads ONE uvd
// float4 {u0,u1,u2,dot}. Values identical to update_sv -> bitwise output.
// ---------------------------------------------------------------------------
template<int MODE>
__global__ __launch_bounds__(256, 2) void mlp_fused_kernel(
    const float* __restrict__ s, const float* __restrict__ nrm,
    const ushort_t* __restrict__ W1h, const ushort_t* __restrict__ W1l,
    const float* __restrict__ b1,
    const ushort_t* __restrict__ W2h, const ushort_t* __restrict__ W2l,
    const float* __restrict__ b2,
    ushort_t* __restrict__ out_b,
    const float4* __restrict__ uvd,    // MODE>=1: {u0,u1,u2,dot} per (m,g)
    float* s_out, float* vbuf,         // MODE>=1: s (rw), v (rw, planar 3xSP)
    float* outv,                       // MODE 1: interleaved v out
    const ushort_t* __restrict__ pW1h, const ushort_t* __restrict__ pW1l,
    const float* __restrict__ pb1,     // MODE 2: next-layer phi weights
    const ushort_t* __restrict__ pW2h, const ushort_t* __restrict__ pW2l,
    const float* __restrict__ pb2,
    ushort_t* __restrict__ pout,       // MODE 2: phi_b out
    int M, int K1, int SP)
{
    __shared__ __align__(16) ushort_t Ah[64 * 40];
    __shared__ __align__(16) ushort_t Al[64 * 40];
    __shared__ __align__(16) ushort_t Wh[128 * 40];
    __shared__ __align__(16) ushort_t Wl[128 * 40];
    __shared__ __align__(16) ushort_t Hh[64 * 136];
    __shared__ __align__(16) ushort_t Hl[64 * 136];

    const int t    = threadIdx.x;
    const int m0   = blockIdx.x * 64;
    const int wv   = t >> 6;
    const int lane = t & 63;
    const int wn   = wv * 32;         // wave's 32-col slice
    const int lr   = lane & 15;
    const int lk   = (lane >> 4) * 8;
    const int quad = lane >> 4;
    const int arow = t >> 3;          // 0..31, 2 passes of 32 rows
    const int acol = (t & 7) * 4;     // fp32 x4
    const int wrow = t >> 2;          // 0..63, 2 passes of 64 rows
    const int wcol = (t & 3) * 8;     // ushort x8

    floatx4 acc[4][2] = {};

    // ---- stage 1: h = silu(A1 @ W1^T + b1) ----
    for (int k0 = 0; k0 < K1; k0 += 32) {
        #pragma unroll
        for (int h = 0; h < 2; ++h) {
            int r = arow + h * 32;
            int m = m0 + r; if (m >= M) m = M - 1;   // clamp tail (in-block)
            float xs[4];
            if (k0 < 128) {
                float4 av = *(const float4*)(s + (long)m * 128 + k0 + acol);
                xs[0] = av.x; xs[1] = av.y; xs[2] = av.z; xs[3] = av.w;
            } else {
                float4 av = *(const float4*)(nrm + (long)m * 128 + (k0 - 128) + acol);
                xs[0] = av.x; xs[1] = av.y; xs[2] = av.z; xs[3] = av.w;
            }
            unsigned short hh[4], ll[4];
            #pragma unroll
            for (int q = 0; q < 4; ++q) {
                hh[q] = f2b(xs[q]);
                ll[q] = f2b(xs[q] - b2f(hh[q]));
            }
            *(ushort4*)(&Ah[r * 40 + acol]) = make_ushort4(hh[0], hh[1], hh[2], hh[3]);
            *(ushort4*)(&Al[r * 40 + acol]) = make_ushort4(ll[0], ll[1], ll[2], ll[3]);
        }
        #pragma unroll
        for (int h = 0; h < 2; ++h) {
            int r = wrow + h * 64;
            *(uint4*)(&Wh[r * 40 + wcol]) =
                *(const uint4*)(W1h + (long)r * K1 + k0 + wcol);
            *(uint4*)(&Wl[r * 40 + wcol]) =
                *(const uint4*)(W1l + (long)r * K1 + k0 + wcol);
        }
        __syncthreads();
        short8 af[4], alf[4], wf[2], wlf[2];
        #pragma unroll
        for (int i = 0; i < 4; ++i) {
            af[i]  = *(const short8*)(&Ah[(i * 16 + lr) * 40 + lk]);
            alf[i] = *(const short8*)(&Al[(i * 16 + lr) * 40 + lk]);
        }
        #pragma unroll
        for (int j = 0; j < 2; ++j) {
            wf[j]  = *(const short8*)(&Wh[(wn + j * 16 + lr) * 40 + lk]);
            wlf[j] = *(const short8*)(&Wl[(wn + j * 16 + lr) * 40 + lk]);
        }
        #pragma unroll
        for (int i = 0; i < 4; ++i)
            #pragma unroll
            for (int j = 0; j < 2; ++j) {
                acc[i][j] = __builtin_amdgcn_mfma_f32_16x16x32_bf16(
                    af[i], wf[j], acc[i][j], 0, 0, 0);
                acc[i][j] = __builtin_amdgcn_mfma_f32_16x16x32_bf16(
                    af[i], wlf[j], acc[i][j], 0, 0, 0);
                acc[i][j] = __builtin_amdgcn_mfma_f32_16x16x32_bf16(
                    alf[i], wf[j], acc[i][j], 0, 0, 0);
            }
        __syncthreads();
    }

    // stage-1 epilogue -> h in LDS (hi/lo), C/D layout col=lane&15, row=quad*4+r
    #pragma unroll
    for (int i = 0; i < 4; ++i)
        #pragma unroll
        for (int r = 0; r < 4; ++r) {
            int mrow = i * 16 + quad * 4 + r;
            #pragma unroll
            for (int j = 0; j < 2; ++j) {
                int kcol = wn + j * 16 + lr;
                float x = acc[i][j][r] + b1[kcol];
                x *= 1.f / (1.f + __expf(-x));
                unsigned short hh = f2b(x);
                Hh[mrow * 136 + kcol] = hh;
                Hl[mrow * 136 + kcol] = f2b(x - b2f(hh));
            }
        }

    // ---- stage 2: 3 n-tiles of 128; MODE>=1 keeps all accumulators ----
    floatx4 accS[3][4][2];
    #pragma unroll
    for (int nt = 0; nt < 3; ++nt) {
        floatx4 a2c[4][2] = {};
        for (int k0 = 0; k0 < 128; k0 += 32) {
            __syncthreads();   // guard Wh/Wl overwrite (and H writes on 1st pass)
            #pragma unroll
            for (int h = 0; h < 2; ++h) {
                int r = wrow + h * 64;
                long wo = (long)(nt * 128 + r) * 128;
                *(uint4*)(&Wh[r * 40 + wcol]) = *(const uint4*)(W2h + wo + k0 + wcol);
                *(uint4*)(&Wl[r * 40 + wcol]) = *(const uint4*)(W2l + wo + k0 + wcol);
            }
            __syncthreads();
            short8 af[4], alf[4], wf[2], wlf[2];
            #pragma unroll
            for (int i = 0; i < 4; ++i) {
                af[i]  = *(const short8*)(&Hh[(i * 16 + lr) * 136 + k0 + lk]);
                alf[i] = *(const short8*)(&Hl[(i * 16 + lr) * 136 + k0 + lk]);
            }
            #pragma unroll
            for (int j = 0; j < 2; ++j) {
                wf[j]  = *(const short8*)(&Wh[(wn + j * 16 + lr) * 40 + lk]);
                wlf[j] = *(const short8*)(&Wl[(wn + j * 16 + lr) * 40 + lk]);
            }
            #pragma unroll
            for (int i = 0; i < 4; ++i)
                #pragma unroll
                for (int j = 0; j < 2; ++j) {
                    a2c[i][j] = __builtin_amdgcn_mfma_f32_16x16x32_bf16(
                        af[i], wf[j], a2c[i][j], 0, 0, 0);
                    a2c[i][j] = __builtin_amdgcn_mfma_f32_16x16x32_bf16(
                        af[i], wlf[j], a2c[i][j], 0, 0, 0);
                    a2c[i][j] = __builtin_amdgcn_mfma_f32_16x16x32_bf16(
                        alf[i], wf[j], a2c[i][j], 0, 0, 0);
                }
        }
        if (MODE >= 1) {
            #pragma unroll
            for (int i = 0; i < 4; ++i)
                #pragma unroll
                for (int j = 0; j < 2; ++j)
                    accS[nt][i][j] = a2c[i][j];
        } else {
            #pragma unroll
            for (int i = 0; i < 4; ++i)
                #pragma unroll
                for (int r = 0; r < 4; ++r) {
                    int m = m0 + i * 16 + quad * 4 + r;
                    if (m >= M) continue;
                    #pragma unroll
                    for (int j = 0; j < 2; ++j) {
                        int n = nt * 128 + wn + j * 16 + lr;
                        out_b[(long)m * 384 + n] = f2b(a2c[i][j][r] + b2[n]);
                    }
                }
        }
    }

    // ---- fused update epilogue (gate modes): update_sv arithmetic in-place ----
    if (MODE >= 1) {
        if (MODE == 2) __syncthreads();   // all waves done reading H (stage 2)
        #pragma unroll
        for (int i = 0; i < 4; ++i)
            #pragma unroll
            for (int r = 0; r < 4; ++r) {
                int m = m0 + i * 16 + quad * 4 + r;
                if (m >= M) continue;
                #pragma unroll
                for (int j = 0; j < 2; ++j) {
                    int g = wn + j * 16 + lr;
                    long idx = (long)m * 128 + g;
                    float a0 = accS[0][i][j][r] + b2[g];
                    float a1 = accS[1][i][j][r] + b2[128 + g];
                    float a2 = accS[2][i][j][r] + b2[256 + g];
                    float4 ud = uvd[idx];            // {u0,u1,u2,dot}
                    float sn = s[idx] + ud.w * a1 + a2;
                    s_out[idx] = sn;
                    if (MODE == 2) {
                        int mrow = i * 16 + quad * 4 + r;
                        unsigned short sh = f2b(sn);
                        Hh[mrow * 136 + g] = sh;           // s_new -> LDS for
                        Hl[mrow * 136 + g] = f2b(sn - b2f(sh));  // chained phi
                    }
                    float x0 = vbuf[idx]          + ud.x * a0;
                    float x1 = vbuf[SP + idx]     + ud.y * a0;
                    float x2 = vbuf[2 * SP + idx] + ud.z * a0;
                    if (MODE == 1 && outv) {
                        outv[idx * 3 + 0] = x0;
                        outv[idx * 3 + 1] = x1;
                        outv[idx * 3 + 2] = x2;
                    } else {
                        vbuf[idx]          = x0;
                        vbuf[SP + idx]     = x1;
                        vbuf[2 * SP + idx] = x2;
                    }
                }
            }
    }

    // ---- MODE 2: chained next-layer phi-MLP (A = s_new from LDS) ----
    if (MODE == 2) {
        __syncthreads();   // s_new visible in Hh/Hl
        floatx4 pacc[4][2] = {};
        for (int k0 = 0; k0 < 128; k0 += 32) {
            __syncthreads();                  // guard Wh/Wl overwrite
            #pragma unroll
            for (int h = 0; h < 2; ++h) {
                int r = wrow + h * 64;
                *(uint4*)(&Wh[r * 40 + wcol]) =
                    *(const uint4*)(pW1h + (long)r * 128 + k0 + wcol);
                *(uint4*)(&Wl[r * 40 + wcol]) =
                    *(const uint4*)(pW1l + (long)r * 128 + k0 + wcol);
            }
            __syncthreads();
            short8 af[4], alf[4], wf[2], wlf[2];
            #pragma unroll
            for (int i = 0; i < 4; ++i) {
                af[i]  = *(const short8*)(&Hh[(i * 16 + lr) * 136 + k0 + lk]);
                alf[i] = *(const short8*)(&Hl[(i * 16 + lr) * 136 + k0 + lk]);
            }
            #pragma unroll
            for (int j = 0; j < 2; ++j) {
                wf[j]  = *(const short8*)(&Wh[(wn + j * 16 + lr) * 40 + lk]);
                wlf[j] = *(const short8*)(&Wl[(wn + j * 16 + lr) * 40 + lk]);
            }
            #pragma unroll
            for (int i = 0; i < 4; ++i)
                #pragma unroll
                for (int j = 0; j < 2; ++j) {
                    pacc[i][j] = __builtin_amdgcn_mfma_f32_16x16x32_bf16(
                        af[i], wf[j], pacc[i][j], 0, 0, 0);
                    pacc[i][j] = __builtin_amdgcn_mfma_f32_16x16x32_bf16(
                        af[i], wlf[j], pacc[i][j], 0, 0, 0);
                    pacc[i][j] = __builtin_amdgcn_mfma_f32_16x16x32_bf16(
                        alf[i], wf[j], pacc[i][j], 0, 0, 0);
                }
        }
        __syncthreads();   // all waves done reading s_new; h may overwrite
        #pragma unroll
        for (int i = 0; i < 4; ++i)
            #pragma unroll
            for (int r = 0; r < 4; ++r) {
                int mrow = i * 16 + quad * 4 + r;
                #pragma unroll
                for (int j = 0; j < 2; ++j) {
                    int kcol = wn + j * 16 + lr;
                    float x = pacc[i][j][r] + pb1[kcol];
                    x *= 1.f / (1.f + __expf(-x));
                    unsigned short hh = f2b(x);
                    Hh[mrow * 136 + kcol] = hh;
                    Hl[mrow * 136 + kcol] = f2b(x - b2f(hh));
                }
            }
        for (int nt = 0; nt < 3; ++nt) {
            floatx4 c2[4][2] = {};
            for (int k0 = 0; k0 < 128; k0 += 32) {
                __syncthreads();   // covers h-write visibility + Wh overwrite
                #pragma unroll
                for (int h = 0; h < 2; ++h) {
                    int r = wrow + h * 64;
                    long wo = (long)(nt * 128 + r) * 128;
                    *(uint4*)(&Wh[r * 40 + wcol]) =
                        *(const uint4*)(pW2h + wo + k0 + wcol);
                    *(uint4*)(&Wl[r * 40 + wcol]) =
                        *(const uint4*)(pW2l + wo + k0 + wcol);
                }
                __syncthreads();
                short8 af[4], alf[4], wf[2], wlf[2];
                #pragma unroll
                for (int i = 0; i < 4; ++i) {
                    af[i]  = *(const short8*)(&Hh[(i * 16 + lr) * 136 + k0 + lk]);
                    alf[i] = *(const short8*)(&Hl[(i * 16 + lr) * 136 + k0 + lk]);
                }
                #pragma unroll
                for (int j = 0; j < 2; ++j) {
                    wf[j]  = *(const short8*)(&Wh[(wn + j * 16 + lr) * 40 + lk]);
                    wlf[j] = *(const short8*)(&Wl[(wn + j * 16 + lr) * 40 + lk]);
                }
                #pragma unroll
                for (int i = 0; i < 4; ++i)
                    #pragma unroll
                    for (int j = 0; j < 2; ++j) {
                        c2[i][j] = __builtin_amdgcn_mfma_f32_16x16x32_bf16(
                            af[i], wf[j], c2[i][j], 0, 0, 0);
                        c2[i][j] = __builtin_amdgcn_mfma_f32_16x16x32_bf16(
                            af[i], wlf[j], c2[i][j], 0, 0, 0);
                        c2[i][j] = __builtin_amdgcn_mfma_f32_16x16x32_bf16(
                            alf[i], wf[j], c2[i][j], 0, 0, 0);
                    }
            }
            #pragma unroll
            for (int i = 0; i < 4; ++i)
                #pragma unroll
                for (int r = 0; r < 4; ++r) {
                    int m = m0 + i * 16 + quad * 4 + r;
                    if (m >= M) continue;
                    #pragma unroll
                    for (int j = 0; j < 2; ++j) {
                        int n = nt * 128 + wn + j * 16 + lr;
                        pout[(long)m * 384 + n] = f2b(c2[i][j][r] + pb2[n]);
                    }
                }
        }
    }
}

// ---------------------------------------------------------------------------
// Fused U+V GEMM over vn in [node][4comp][feat] layout (comp3 = zero).
// Rows 4n..4n+3 of A are the 4 comps of node n; MFMA C/D layout gives each
// thread 4 CONSECUTIVE rows in acc[.][.][0..3] -> all comps of one node.
// Epilogue emits uvd = {u0,u1,u2,dot(u,v)} (float4) and nrm = |v| directly,
// eliminating the u_v/v_v round-trip (~92 MB/layer). Values are the same
// fp32 accumulators previously stored+reloaded -> bitwise-identical output.
// ---------------------------------------------------------------------------
__global__ __launch_bounds__(256, 2) void gemm_uv_kernel(
    const ushort_t* __restrict__ Ahg, const ushort_t* __restrict__ Alg,
    const ushort_t* __restrict__ Uh, const ushort_t* __restrict__ Ul,
    const ushort_t* __restrict__ Vh, const ushort_t* __restrict__ Vl,
    float4* __restrict__ uvd, float* __restrict__ nrm,
    int Mr)                                     // Mr = 4N rows, K = 128
{
    __shared__ __align__(16) ushort_t Ah[128 * 40];
    __shared__ __align__(16) ushort_t Al[128 * 40];
    __shared__ __align__(16) ushort_t WUh[128 * 40];
    __shared__ __align__(16) ushort_t WUl[128 * 40];
    __shared__ __align__(16) ushort_t WVh[128 * 40];
    __shared__ __align__(16) ushort_t WVl[128 * 40];
    const int t    = threadIdx.x;
    const int m0   = blockIdx.x * 128;
    const int wv   = t >> 6;
    const int lane = t & 63;
    const int wm   = (wv >> 1) * 64;
    const int wn   = (wv & 1) * 64;
    const int lr   = lane & 15;
    const int lk   = (lane >> 4) * 8;
    const int quad = lane >> 4;
    const int srow = t >> 2;
    const int scol = (t & 3) * 8;

    floatx4 aU[4][4] = {};
    floatx4 aV[4][4] = {};

    for (int k0 = 0; k0 < 128; k0 += 32) {
        #pragma unroll
        for (int h = 0; h < 2; ++h) {
            int r = srow + h * 64;
            int m = m0 + r; if (m >= Mr) m = Mr - 1;
            *(uint4*)(&Ah[r * 40 + scol])  = *(const uint4*)(Ahg + (long)m * 128 + k0 + scol);
            *(uint4*)(&Al[r * 40 + scol])  = *(const uint4*)(Alg + (long)m * 128 + k0 + scol);
            *(uint4*)(&WUh[r * 40 + scol]) = *(const uint4*)(Uh + (long)r * 128 + k0 + scol);
            *(uint4*)(&WUl[r * 40 + scol]) = *(const uint4*)(Ul + (long)r * 128 + k0 + scol);
            *(uint4*)(&WVh[r * 40 + scol]) = *(const uint4*)(Vh + (long)r * 128 + k0 + scol);
            *(uint4*)(&WVl[r * 40 + scol]) = *(const uint4*)(Vl + (long)r * 128 + k0 + scol);
        }
        __syncthreads();
        short8 ah[4], al[4];
        #pragma unroll
        for (int i = 0; i < 4; ++i) {
            ah[i] = *(const short8*)(&Ah[(wm + i * 16 + lr) * 40 + lk]);
            al[i] = *(const short8*)(&Al[(wm + i * 16 + lr) * 40 + lk]);
        }
        #pragma unroll
        for (int j = 0; j < 4; ++j) {
            short8 wuh = *(const short8*)(&WUh[(wn + j * 16 + lr) * 40 + lk]);
            short8 wul = *(const short8*)(&WUl[(wn + j * 16 + lr) * 40 + lk]);
            short8 wvh = *(const short8*)(&WVh[(wn + j * 16 + lr) * 40 + lk]);
            short8 wvl = *(const short8*)(&WVl[(wn + j * 16 + lr) * 40 + lk]);
            #pragma unroll
            for (int i = 0; i < 4; ++i) {
                aU[i][j] = __builtin_amdgcn_mfma_f32_16x16x32_bf16(
                    ah[i], wuh, aU[i][j], 0, 0, 0);
                aU[i][j] = __builtin_amdgcn_mfma_f32_16x16x32_bf16(
                    ah[i], wul, aU[i][j], 0, 0, 0);
                aU[i][j] = __builtin_amdgcn_mfma_f32_16x16x32_bf16(
                    al[i], wuh, aU[i][j], 0, 0, 0);
                aV[i][j] = __builtin_amdgcn_mfma_f32_16x16x32_bf16(
                    ah[i], wvh, aV[i][j], 0, 0, 0);
                aV[i][j] = __builtin_amdgcn_mfma_f32_16x16x32_bf16(
                    ah[i], wvl, aV[i][j], 0, 0, 0);
                aV[i][j] = __builtin_amdgcn_mfma_f32_16x16x32_bf16(
                    al[i], wvh, aV[i][j], 0, 0, 0);
            }
        }
        __syncthreads();
    }

    #pragma unroll
    for (int i = 0; i < 4; ++i) {
        int mbase = m0 + wm + i * 16 + quad * 4;   // multiple of 4
        if (mbase >= Mr) continue;
        int node = mbase >> 2;
        #pragma unroll
        for (int j = 0; j < 4; ++j) {
            int n = wn + j * 16 + lr;
            float u0 = aU[i][j][0], u1 = aU[i][j][1], u2 = aU[i][j][2];
            float w0 = aV[i][j][0], w1 = aV[i][j][1], w2 = aV[i][j][2];
            float dot = u0 * w0 + u1 * w1 + u2 * w2;
            uvd[(long)node * 128 + n] = make_float4(u0, u1, u2, dot);
            nrm[(long)node * 128 + n] = sqrtf(w0 * w0 + w1 * w1 + w2 * w2);
        }
    }
}

// ---------------------------------------------------------------------------
__global__ __launch_bounds__(256) void split_kernel(
    const float* __restrict__ src, ushort_t* __restrict__ hi,
    ushort_t* __restrict__ lo, int n)
{
    int i = blockIdx.x * blockDim.x + threadIdx.x;
    if (i >= n) return;
    float x = src[i];
    unsigned short h = f2b(x);
    hi[i] = h;
    lo[i] = f2b(x - b2f(h));
}

// ---------------------------------------------------------------------------
// CSR build
// ---------------------------------------------------------------------------
__global__ __launch_bounds__(256) void hist_kernel(
    const int* __restrict__ nbr, int* __restrict__ deg, int Ed)
{
    int e = blockIdx.x * blockDim.x + threadIdx.x;
    if (e >= Ed) return;
    int E = Ed >> 1;
    int i = (e < E) ? nbr[2 * e] : nbr[2 * (e - E) + 1];
    atomicAdd(&deg[i], 1);
}

__device__ inline int wave_incl_scan(int x, int lane)
{
    #pragma unroll
    for (int s = 1; s < 64; s <<= 1) {
        int y = __shfl_up(x, s, 64);
        if (lane >= s) x += y;
    }
    return x;
}

__global__ __launch_bounds__(1024) void scan_kernel(
    const int* __restrict__ deg, int* __restrict__ off,
    int* __restrict__ cursor, int N)
{
    __shared__ int wsum[16];
    __shared__ int carry_s;
    const int t = threadIdx.x;
    const int lane = t & 63;
    const int w = t >> 6;
    if (t == 0) { carry_s = 0; off[0] = 0; }
    __syncthreads();
    for (int base = 0; base < N; base += 1024) {
        int i = base + t;
        int x = (i < N) ? deg[i] : 0;
        int sc = wave_incl_scan(x, lane);
        if (lane == 63) wsum[w] = sc;
        __syncthreads();
        if (w == 0) {
            int v = (lane < 16) ? wsum[lane] : 0;
            int vs = wave_incl_scan(v, lane);
            if (lane < 16) wsum[lane] = vs;
        }
        __syncthreads();
        int waveoff = (w > 0) ? wsum[w - 1] : 0;
        int inc = sc + waveoff + carry_s;
        if (i < N) { off[i + 1] = inc; cursor[i] = inc - x; }
        __syncthreads();
        if (t == 1023) carry_s = inc;
        __syncthreads();
    }
}

__global__ __launch_bounds__(256) void scatter_geom_kernel(
    const int* __restrict__ nbr, const float* __restrict__ xyz,
    int* __restrict__ cursor, int* __restrict__ csr_j,
    float* __restrict__ csr_env, float* __restrict__ csr_unit,
    float* __restrict__ csr_rbfe, int Ed)
{
    int e = blockIdx.x * blockDim.x + threadIdx.x;
    if (e >= Ed) return;
    int E = Ed >> 1;
    int i, j;
    if (e < E) { i = nbr[2 * e];         j = nbr[2 * e + 1]; }
    else       { int u = e - E; i = nbr[2 * u + 1]; j = nbr[2 * u]; }

    int p = atomicAdd(&cursor[i], 1);
    csr_j[p] = j;

    float rx = xyz[3 * j + 0] - xyz[3 * i + 0];
    float ry = xyz[3 * j + 1] - xyz[3 * i + 1];
    float rz = xyz[3 * j + 2] - xyz[3 * i + 2];
    float d   = sqrtf(rx * rx + ry * ry + rz * rz);
    float inv = 1.f / d;
    csr_unit[3 * p + 0] = rx * inv;
    csr_unit[3 * p + 1] = ry * inv;
    csr_unit[3 * p + 2] = rz * inv;
    float ev = (d < 20.f) ? 0.5f * (__cosf(PI_F * d / 20.f) + 1.f) : 0.f;
    csr_env[p] = ev;
    float base = PI_F * d / 20.f;
    #pragma unroll
    for (int k = 0; k < NRBF; ++k)
        csr_rbfe[(long)p * NRBF + k] = ev * __sinf((float)(k + 1) * base) * inv;
}

// ---------------------------------------------------------------------------
// Edge aggregation — EXACT R0 inner loop, grid 2048 (proven optimum).
// vnh/vnl stores in [node][4comp][feat] layout (comp3 pre-zeroed once).
// ---------------------------------------------------------------------------
__global__ __launch_bounds__(128) void edge_aggr_kernel(
    const int* __restrict__ off, const int* __restrict__ csr_j,
    const float* __restrict__ csr_env, const float* __restrict__ csr_unit,
    const float* __restrict__ csr_rbfe,
    const ushort_t* __restrict__ phib, const float* __restrict__ vold,
    const float* __restrict__ distW, const float* __restrict__ distb,
    float* __restrict__ s, float* __restrict__ vnew,
    ushort_t* __restrict__ vnh, ushort_t* __restrict__ vnl, int N, int SP)
{
    const int f = threadIdx.x;
    float w0c[NRBF], w1c[NRBF], w2c[NRBF];
    const float b0 = distb[f];
    const float b1 = distb[128 + f];
    const float b2 = distb[256 + f];
    #pragma unroll
    for (int k = 0; k < NRBF; ++k) {
        w0c[k] = distW[(long)f * NRBF + k];
        w1c[k] = distW[(long)(128 + f) * NRBF + k];
        w2c[k] = distW[(long)(256 + f) * NRBF + k];
    }

    for (int node = blockIdx.x; node < N; node += gridDim.x) {
        const int p0 = off[node], p1 = off[node + 1];
        float ssum = 0.f, v0 = 0.f, v1 = 0.f, v2 = 0.f;
        for (int p = p0; p < p1; ++p) {
            int j = csr_j[p];
            float ev = csr_env[p];
            float ux = csr_unit[3 * p + 0];
            float uy = csr_unit[3 * p + 1];
            float uz = csr_unit[3 * p + 2];
            const float* rb = csr_rbfe + (long)p * NRBF;
            float w0 = ev * b0, w1 = ev * b1, w2 = ev * b2;
            #pragma unroll
            for (int k = 0; k < NRBF; ++k) {
                float r = rb[k];
                w0 += r * w0c[k];
                w1 += r * w1c[k];
                w2 += r * w2c[k];
            }
            long jb = (long)j * 384;
            float i0 = b2f(phib[jb + f])       * w0;
            float i1 = b2f(phib[jb + 128 + f]) * w1;
            float i2 = b2f(phib[jb + 256 + f]) * w2;
            long jv = (long)j * FEAT + f;
            ssum += i1;
            v0 += i2 * ux + i0 * vold[jv];
            v1 += i2 * uy + i0 * vold[SP + jv];
            v2 += i2 * uz + i0 * vold[2 * SP + jv];
        }
        long iv = (long)node * FEAT + f;
        s[iv] += ssum;
        float n0 = vold[iv]          + v0;
        float n1 = vold[SP + iv]     + v1;
        float n2 = vold[2 * SP + iv] + v2;
        vnew[iv]          = n0;
        vnew[SP + iv]     = n1;
        vnew[2 * SP + iv] = n2;
        unsigned short h0 = f2b(n0), h1 = f2b(n1), h2 = f2b(n2);
        long ib = (long)node * 512 + f;      // [node][4comp][feat] layout
        vnh[ib]       = h0;  vnl[ib]       = f2b(n0 - b2f(h0));
        vnh[ib + 128] = h1;  vnl[ib + 128] = f2b(n1 - b2f(h1));
        vnh[ib + 256] = h2;  vnl[ib + 256] = f2b(n2 - b2f(h2));
    }
}

// ---------------------------------------------------------------------------
// Elementwise kernels
// ---------------------------------------------------------------------------
__global__ __launch_bounds__(256) void init_s_kernel(
    const float* __restrict__ cg_s, float* __restrict__ s,
    float* __restrict__ vA, int nS, int nV)
{
    int idx = blockIdx.x * blockDim.x + threadIdx.x;
    if (idx < nS) s[idx] = cg_s[idx];
    if (idx < nV) vA[idx] = 0.f;
}

// ---------------------------------------------------------------------------
extern "C" void kernel_launch(void* const* d_in, const int* in_sizes, int n_in,
                              void* d_out, int out_size, void* d_ws, size_t ws_size,
                              hipStream_t stream)
{
    const float* xyz     = (const float*)d_in[0];
    const int*   nbr     = (const int*)  d_in[1];
    const float* cg_s    = (const float*)d_in[2];
    const float* msg_W1  = (const float*)d_in[3];
    const float* msg_b1  = (const float*)d_in[4];
    const float* msg_W2  = (const float*)d_in[5];
    const float* msg_b2  = (const float*)d_in[6];
    const float* dist_W  = (const float*)d_in[7];
    const float* dist_b  = (const float*)d_in[8];
    const float* upd_U   = (const float*)d_in[9];
    const float* upd_V   = (const float*)d_in[10];
    const float* upd_sW1 = (const float*)d_in[11];
    const float* upd_sb1 = (const float*)d_in[12];
    const float* upd_sW2 = (const float*)d_in[13];
    const float* upd_sb2 = (const float*)d_in[14];

    const int E  = in_sizes[1] / 2;
    const int Ed = 2 * E;
    const int N  = in_sizes[2] / FEAT;
    const int SP = N * FEAT;

    float* s    = (float*)d_out;
    float* outv = (float*)d_out + (long)SP;

    // workspace carve-up
    float* w = (float*)d_ws;
    size_t off_ = 0;
    auto alloc = [&](size_t nelem) {
        float* p = w + off_;
        off_ += (nelem + 255) & ~(size_t)255;
        return p;
    };
    auto allocb = [&](size_t nelem) {
        return (ushort_t*)alloc((nelem + 1) / 2);
    };
    int*   deg      = (int*)alloc((size_t)N);
    int*   off      = (int*)alloc((size_t)N + 1);
    int*   cursor   = (int*)alloc((size_t)N);
    int*   csr_j    = (int*)alloc((size_t)Ed);
    float* csr_env  = alloc((size_t)Ed);
    float* csr_unit = alloc((size_t)Ed * 3);
    float* csr_rbfe = alloc((size_t)Ed * NRBF);
    float* uvd      = alloc((size_t)4 * SP);   // {u0,u1,u2,dot} per (node,g)
    float* nrm      = alloc((size_t)SP);       // |v_v| per (node,g)
    float* vA       = alloc((size_t)3 * SP);
    float* vB       = alloc((size_t)3 * SP);
    ushort_t* phi_b = allocb((size_t)N * 384);
    ushort_t* vnh   = allocb((size_t)4 * SP);  // [node][4comp][feat], comp3=0
    ushort_t* vnl   = allocb((size_t)4 * SP);
    const int n1 = NCONV * FEAT * FEAT;
    const int n2 = NCONV * 3 * FEAT * FEAT;
    const int n3 = NCONV * FEAT * 2 * FEAT;
    ushort_t* w1h  = allocb((size_t)n1);
    ushort_t* w1l  = allocb((size_t)n1);
    ushort_t* w2h  = allocb((size_t)n2);
    ushort_t* w2l  = allocb((size_t)n2);
    ushort_t* uh   = allocb((size_t)n1);
    ushort_t* ul   = allocb((size_t)n1);
    ushort_t* vh   = allocb((size_t)n1);
    ushort_t* vl   = allocb((size_t)n1);
    ushort_t* sw1h = allocb((size_t)n3);
    ushort_t* sw1l = allocb((size_t)n3);
    ushort_t* sw2h = allocb((size_t)n2);
    ushort_t* sw2l = allocb((size_t)n2);
    (void)ws_size; (void)n_in; (void)out_size;

    // weight split (once per launch)
    split_kernel<<<(n1 + 255) / 256, 256, 0, stream>>>(msg_W1, w1h, w1l, n1);
    split_kernel<<<(n2 + 255) / 256, 256, 0, stream>>>(msg_W2, w2h, w2l, n2);
    split_kernel<<<(n1 + 255) / 256, 256, 0, stream>>>(upd_U, uh, ul, n1);
    split_kernel<<<(n1 + 255) / 256, 256, 0, stream>>>(upd_V, vh, vl, n1);
    split_kernel<<<(n3 + 255) / 256, 256, 0, stream>>>(upd_sW1, sw1h, sw1l, n3);
    split_kernel<<<(n2 + 255) / 256, 256, 0, stream>>>(upd_sW2, sw2h, sw2l, n2);

    // init s <- cg_s, vA <- 0; zero vnh/vnl once (comp3 stays 0 across layers)
    {
        int n = 3 * SP;
        init_s_kernel<<<(n + 255) / 256, 256, 0, stream>>>(cg_s, s, vA, SP, n);
        hipMemsetAsync(vnh, 0, (size_t)4 * SP * sizeof(ushort_t), stream);
        hipMemsetAsync(vnl, 0, (size_t)4 * SP * sizeof(ushort_t), stream);
    }

    // CSR build (once per launch)
    hipMemsetAsync(deg, 0, (size_t)N * sizeof(int), stream);
    hist_kernel<<<(Ed + 255) / 256, 256, 0, stream>>>(nbr, deg, Ed);
    scan_kernel<<<1, 1024, 0, stream>>>(deg, off, cursor, N);
    scatter_geom_kernel<<<(Ed + 255) / 256, 256, 0, stream>>>(
        nbr, xyz, cursor, csr_j, csr_env, csr_unit, csr_rbfe, Ed);

    float* vold = vA;
    float* vnew = vB;
    dim3 gM((N + 63) / 64, 1);
    dim3 gUV((4 * N + 127) / 128, 1);
    int edgeGrid = 2048;
    if (edgeGrid > N) edgeGrid = N;

    for (int l = 0; l < NCONV; ++l) {
        const float* b2  = msg_b2  + (long)l * 3 * FEAT;
        const float* dW  = dist_W  + (long)l * 3 * FEAT * NRBF;
        const float* db  = dist_b  + (long)l * 3 * FEAT;
        const float* sb1 = upd_sb1 + (long)l * FEAT;
        const float* sb2 = upd_sb2 + (long)l * 3 * FEAT;
        const long o1 = (long)l * FEAT * FEAT;
        const long o2 = (long)l * 3 * FEAT * FEAT;
        const long o3 = (long)l * FEAT * 2 * FEAT;

        // phi-MLP for layer 0 only; layers 1,2 get phi from the chained MODE 2
        if (l == 0) {
            const float* b1 = msg_b1;
            mlp_fused_kernel<0><<<gM, 256, 0, stream>>>(
                s, nullptr, w1h, w1l, b1, w2h, w2l, b2,
                phi_b, nullptr, nullptr, nullptr, nullptr,
                nullptr, nullptr, nullptr, nullptr, nullptr, nullptr, nullptr,
                N, FEAT, SP);
        }

        // atomic-free message aggregation (R0 loop, 2048 persistent blocks)
        edge_aggr_kernel<<<edgeGrid, 128, 0, stream>>>(
            off, csr_j, csr_env, csr_unit, csr_rbfe, phi_b, vold,
            dW, db, s, vnew, vnh, vnl, N, SP);

        // fused U+V GEMM -> uvd {u0,u1,u2,dot} + nrm
        gemm_uv_kernel<<<gUV, 256, 0, stream>>>(
            vnh, vnl, uh + o1, ul + o1, vh + o1, vl + o1,
            (float4*)uvd, nrm, 4 * N);

        if (l < NCONV - 1) {
            // gate-MLP + update + CHAINED phi-MLP of layer l+1
            const long o1n = (long)(l + 1) * FEAT * FEAT;
            const long o2n = (long)(l + 1) * 3 * FEAT * FEAT;
            const float* pb1 = msg_b1 + (long)(l + 1) * FEAT;
            const float* pb2 = msg_b2 + (long)(l + 1) * 3 * FEAT;
            mlp_fused_kernel<2><<<gM, 256, 0, stream>>>(
                s, nrm, sw1h + o3, sw1l + o3, sb1, sw2h + o2, sw2l + o2, sb2,
                nullptr, (const float4*)uvd, s, vnew, nullptr,
                w1h + o1n, w1l + o1n, pb1, w2h + o2n, w2l + o2n, pb2, phi_b,
                N, 2 * FEAT, SP);
        } else {
            // final gate-MLP + update; v written interleaved straight to output
            mlp_fused_kernel<1><<<gM, 256, 0, stream>>>(
                s, nrm, sw1h + o3, sw1l + o3, sb1, sw2h + o2, sw2l + o2, sb2,
                nullptr, (const float4*)uvd, s, vnew, outv,
                nullptr, nullptr, nullptr, nullptr, nullptr, nullptr, nullptr,
                N, 2 * FEAT, SP);
        }

        float* tmp = vold; vold = vnew; vnew = tmp;
    }
}

// Round 16
// 716.393 us; speedup vs baseline: 1.1882x; 1.0418x over previous
//
#include <hip/hip_runtime.h>
#include <math.h>

#define FEAT 128
#define NRBF 20
#define NCONV 3
#define PI_F 3.14159265358979323846f

typedef __attribute__((ext_vector_type(8))) short short8;
typedef __attribute__((ext_vector_type(4))) float floatx4;
typedef unsigned short ushort_t;

__device__ inline float b2f(unsigned short u) {
    union { unsigned int i; float f; } c; c.i = ((unsigned int)u) << 16; return c.f;
}
__device__ inline unsigned short f2b(float x) {
    union { float f; unsigned int i; } c; c.f = x;
    unsigned int u = c.i;
    return (unsigned short)((u + 0x7fffu + ((u >> 16) & 1u)) >> 16);
}

// ---------------------------------------------------------------------------
// Fused 2-layer MLP.
// R16: BM 64 -> 32 (R6's proven CU-coverage lever applied again: R14 counters
// showed occupancy 13.6%, MfmaUtil 6% -> coverage-bound). Grid 313 -> 625
// blocks, LDS 64 -> 42.4 KB -> 3 blocks/CU via __launch_bounds__(256,3).
// acc/accS shrink to [..][2][2]; per-output-element MFMA order unchanged ->
// bitwise-identical output.
// MODE 0: phi standalone.  MODE 1: gate+update (final).  MODE 2: gate+update
// + chained next-layer phi.
// ---------------------------------------------------------------------------
template<int MODE>
__global__ __launch_bounds__(256, 3) void mlp_fused_kernel(
    const float* __restrict__ s, const float* __restrict__ nrm,
    const ushort_t* __restrict__ W1h, const ushort_t* __restrict__ W1l,
    const float* __restrict__ b1,
    const ushort_t* __restrict__ W2h, const ushort_t* __restrict__ W2l,
    const float* __restrict__ b2,
    ushort_t* __restrict__ out_b,
    const float4* __restrict__ uvd,    // MODE>=1: {u0,u1,u2,dot} per (m,g)
    float* s_out, float* vbuf,         // MODE>=1: s (rw), v (rw, planar 3xSP)
    float* outv,                       // MODE 1: interleaved v out
    const ushort_t* __restrict__ pW1h, const ushort_t* __restrict__ pW1l,
    const float* __restrict__ pb1,     // MODE 2: next-layer phi weights
    const ushort_t* __restrict__ pW2h, const ushort_t* __restrict__ pW2l,
    const float* __restrict__ pb2,
    ushort_t* __restrict__ pout,       // MODE 2: phi_b out
    int M, int K1, int SP)
{
    __shared__ __align__(16) ushort_t Ah[32 * 40];
    __shared__ __align__(16) ushort_t Al[32 * 40];
    __shared__ __align__(16) ushort_t Wh[128 * 40];
    __shared__ __align__(16) ushort_t Wl[128 * 40];
    __shared__ __align__(16) ushort_t Hh[32 * 136];
    __shared__ __align__(16) ushort_t Hl[32 * 136];

    const int t    = threadIdx.x;
    const int m0   = blockIdx.x * 32;
    const int wv   = t >> 6;
    const int lane = t & 63;
    const int wn   = wv * 32;         // wave's 32-col slice
    const int lr   = lane & 15;
    const int lk   = (lane >> 4) * 8;
    const int quad = lane >> 4;
    const int arow = t >> 3;          // 0..31, ONE pass of 32 rows
    const int acol = (t & 7) * 4;     // fp32 x4
    const int wrow = t >> 2;          // 0..63, 2 passes of 64 rows
    const int wcol = (t & 3) * 8;     // ushort x8

    floatx4 acc[2][2] = {};

    // ---- stage 1: h = silu(A1 @ W1^T + b1) ----
    for (int k0 = 0; k0 < K1; k0 += 32) {
        {
            int r = arow;
            int m = m0 + r; if (m >= M) m = M - 1;   // clamp tail (in-block)
            float xs[4];
            if (k0 < 128) {
                float4 av = *(const float4*)(s + (long)m * 128 + k0 + acol);
                xs[0] = av.x; xs[1] = av.y; xs[2] = av.z; xs[3] = av.w;
            } else {
                float4 av = *(const float4*)(nrm + (long)m * 128 + (k0 - 128) + acol);
                xs[0] = av.x; xs[1] = av.y; xs[2] = av.z; xs[3] = av.w;
            }
            unsigned short hh[4], ll[4];
            #pragma unroll
            for (int q = 0; q < 4; ++q) {
                hh[q] = f2b(xs[q]);
                ll[q] = f2b(xs[q] - b2f(hh[q]));
            }
            *(ushort4*)(&Ah[r * 40 + acol]) = make_ushort4(hh[0], hh[1], hh[2], hh[3]);
            *(ushort4*)(&Al[r * 40 + acol]) = make_ushort4(ll[0], ll[1], ll[2], ll[3]);
        }
        #pragma unroll
        for (int h = 0; h < 2; ++h) {
            int r = wrow + h * 64;
            *(uint4*)(&Wh[r * 40 + wcol]) =
                *(const uint4*)(W1h + (long)r * K1 + k0 + wcol);
            *(uint4*)(&Wl[r * 40 + wcol]) =
                *(const uint4*)(W1l + (long)r * K1 + k0 + wcol);
        }
        __syncthreads();
        short8 af[2], alf[2], wf[2], wlf[2];
        #pragma unroll
        for (int i = 0; i < 2; ++i) {
            af[i]  = *(const short8*)(&Ah[(i * 16 + lr) * 40 + lk]);
            alf[i] = *(const short8*)(&Al[(i * 16 + lr) * 40 + lk]);
        }
        #pragma unroll
        for (int j = 0; j < 2; ++j) {
            wf[j]  = *(const short8*)(&Wh[(wn + j * 16 + lr) * 40 + lk]);
            wlf[j] = *(const short8*)(&Wl[(wn + j * 16 + lr) * 40 + lk]);
        }
        #pragma unroll
        for (int i = 0; i < 2; ++i)
            #pragma unroll
            for (int j = 0; j < 2; ++j) {
                acc[i][j] = __builtin_amdgcn_mfma_f32_16x16x32_bf16(
                    af[i], wf[j], acc[i][j], 0, 0, 0);
                acc[i][j] = __builtin_amdgcn_mfma_f32_16x16x32_bf16(
                    af[i], wlf[j], acc[i][j], 0, 0, 0);
                acc[i][j] = __builtin_amdgcn_mfma_f32_16x16x32_bf16(
                    alf[i], wf[j], acc[i][j], 0, 0, 0);
            }
        __syncthreads();
    }

    // stage-1 epilogue -> h in LDS (hi/lo), C/D layout col=lane&15, row=quad*4+r
    #pragma unroll
    for (int i = 0; i < 2; ++i)
        #pragma unroll
        for (int r = 0; r < 4; ++r) {
            int mrow = i * 16 + quad * 4 + r;
            #pragma unroll
            for (int j = 0; j < 2; ++j) {
                int kcol = wn + j * 16 + lr;
                float x = acc[i][j][r] + b1[kcol];
                x *= 1.f / (1.f + __expf(-x));
                unsigned short hh = f2b(x);
                Hh[mrow * 136 + kcol] = hh;
                Hl[mrow * 136 + kcol] = f2b(x - b2f(hh));
            }
        }

    // ---- stage 2: 3 n-tiles of 128; MODE>=1 keeps all accumulators ----
    floatx4 accS[3][2][2];
    #pragma unroll
    for (int nt = 0; nt < 3; ++nt) {
        floatx4 a2c[2][2] = {};
        for (int k0 = 0; k0 < 128; k0 += 32) {
            __syncthreads();   // guard Wh/Wl overwrite (and H writes on 1st pass)
            #pragma unroll
            for (int h = 0; h < 2; ++h) {
                int r = wrow + h * 64;
                long wo = (long)(nt * 128 + r) * 128;
                *(uint4*)(&Wh[r * 40 + wcol]) = *(const uint4*)(W2h + wo + k0 + wcol);
                *(uint4*)(&Wl[r * 40 + wcol]) = *(const uint4*)(W2l + wo + k0 + wcol);
            }
            __syncthreads();
            short8 af[2], alf[2], wf[2], wlf[2];
            #pragma unroll
            for (int i = 0; i < 2; ++i) {
                af[i]  = *(const short8*)(&Hh[(i * 16 + lr) * 136 + k0 + lk]);
                alf[i] = *(const short8*)(&Hl[(i * 16 + lr) * 136 + k0 + lk]);
            }
            #pragma unroll
            for (int j = 0; j < 2; ++j) {
                wf[j]  = *(const short8*)(&Wh[(wn + j * 16 + lr) * 40 + lk]);
                wlf[j] = *(const short8*)(&Wl[(wn + j * 16 + lr) * 40 + lk]);
            }
            #pragma unroll
            for (int i = 0; i < 2; ++i)
                #pragma unroll
                for (int j = 0; j < 2; ++j) {
                    a2c[i][j] = __builtin_amdgcn_mfma_f32_16x16x32_bf16(
                        af[i], wf[j], a2c[i][j], 0, 0, 0);
                    a2c[i][j] = __builtin_amdgcn_mfma_f32_16x16x32_bf16(
                        af[i], wlf[j], a2c[i][j], 0, 0, 0);
                    a2c[i][j] = __builtin_amdgcn_mfma_f32_16x16x32_bf16(
                        alf[i], wf[j], a2c[i][j], 0, 0, 0);
                }
        }
        if (MODE >= 1) {
            #pragma unroll
            for (int i = 0; i < 2; ++i)
                #pragma unroll
                for (int j = 0; j < 2; ++j)
                    accS[nt][i][j] = a2c[i][j];
        } else {
            #pragma unroll
            for (int i = 0; i < 2; ++i)
                #pragma unroll
                for (int r = 0; r < 4; ++r) {
                    int m = m0 + i * 16 + quad * 4 + r;
                    if (m >= M) continue;
                    #pragma unroll
                    for (int j = 0; j < 2; ++j) {
                        int n = nt * 128 + wn + j * 16 + lr;
                        out_b[(long)m * 384 + n] = f2b(a2c[i][j][r] + b2[n]);
                    }
                }
        }
    }

    // ---- fused update epilogue (gate modes): update_sv arithmetic in-place ----
    if (MODE >= 1) {
        if (MODE == 2) __syncthreads();   // all waves done reading H (stage 2)
        #pragma unroll
        for (int i = 0; i < 2; ++i)
            #pragma unroll
            for (int r = 0; r < 4; ++r) {
                int m = m0 + i * 16 + quad * 4 + r;
                if (m >= M) continue;
                #pragma unroll
                for (int j = 0; j < 2; ++j) {
                    int g = wn + j * 16 + lr;
                    long idx = (long)m * 128 + g;
                    float a0 = accS[0][i][j][r] + b2[g];
                    float a1 = accS[1][i][j][r] + b2[128 + g];
                    float a2 = accS[2][i][j][r] + b2[256 + g];
                    float4 ud = uvd[idx];            // {u0,u1,u2,dot}
                    float sn = s[idx] + ud.w * a1 + a2;
                    s_out[idx] = sn;
                    if (MODE == 2) {
                        int mrow = i * 16 + quad * 4 + r;
                        unsigned short sh = f2b(sn);
                        Hh[mrow * 136 + g] = sh;           // s_new -> LDS for
                        Hl[mrow * 136 + g] = f2b(sn - b2f(sh));  // chained phi
                    }
                    float x0 = vbuf[idx]          + ud.x * a0;
                    float x1 = vbuf[SP + idx]     + ud.y * a0;
                    float x2 = vbuf[2 * SP + idx] + ud.z * a0;
                    if (MODE == 1 && outv) {
                        outv[idx * 3 + 0] = x0;
                        outv[idx * 3 + 1] = x1;
                        outv[idx * 3 + 2] = x2;
                    } else {
                        vbuf[idx]          = x0;
                        vbuf[SP + idx]     = x1;
                        vbuf[2 * SP + idx] = x2;
                    }
                }
            }
    }

    // ---- MODE 2: chained next-layer phi-MLP (A = s_new from LDS) ----
    if (MODE == 2) {
        __syncthreads();   // s_new visible in Hh/Hl
        floatx4 pacc[2][2] = {};
        for (int k0 = 0; k0 < 128; k0 += 32) {
            __syncthreads();                  // guard Wh/Wl overwrite
            #pragma unroll
            for (int h = 0; h < 2; ++h) {
                int r = wrow + h * 64;
                *(uint4*)(&Wh[r * 40 + wcol]) =
                    *(const uint4*)(pW1h + (long)r * 128 + k0 + wcol);
                *(uint4*)(&Wl[r * 40 + wcol]) =
                    *(const uint4*)(pW1l + (long)r * 128 + k0 + wcol);
            }
            __syncthreads();
            short8 af[2], alf[2], wf[2], wlf[2];
            #pragma unroll
            for (int i = 0; i < 2; ++i) {
                af[i]  = *(const short8*)(&Hh[(i * 16 + lr) * 136 + k0 + lk]);
                alf[i] = *(const short8*)(&Hl[(i * 16 + lr) * 136 + k0 + lk]);
            }
            #pragma unroll
            for (int j = 0; j < 2; ++j) {
                wf[j]  = *(const short8*)(&Wh[(wn + j * 16 + lr) * 40 + lk]);
                wlf[j] = *(const short8*)(&Wl[(wn + j * 16 + lr) * 40 + lk]);
            }
            #pragma unroll
            for (int i = 0; i < 2; ++i)
                #pragma unroll
                for (int j = 0; j < 2; ++j) {
                    pacc[i][j] = __builtin_amdgcn_mfma_f32_16x16x32_bf16(
                        af[i], wf[j], pacc[i][j], 0, 0, 0);
                    pacc[i][j] = __builtin_amdgcn_mfma_f32_16x16x32_bf16(
                        af[i], wlf[j], pacc[i][j], 0, 0, 0);
                    pacc[i][j] = __builtin_amdgcn_mfma_f32_16x16x32_bf16(
                        alf[i], wf[j], pacc[i][j], 0, 0, 0);
                }
        }
        __syncthreads();   // all waves done reading s_new; h may overwrite
        #pragma unroll
        for (int i = 0; i < 2; ++i)
            #pragma unroll
            for (int r = 0; r < 4; ++r) {
                int mrow = i * 16 + quad * 4 + r;
                #pragma unroll
                for (int j = 0; j < 2; ++j) {
                    int kcol = wn + j * 16 + lr;
                    float x = pacc[i][j][r] + pb1[kcol];
                    x *= 1.f / (1.f + __expf(-x));
                    unsigned short hh = f2b(x);
                    Hh[mrow * 136 + kcol] = hh;
                    Hl[mrow * 136 + kcol] = f2b(x - b2f(hh));
                }
            }
        for (int nt = 0; nt < 3; ++nt) {
            floatx4 c2[2][2] = {};
            for (int k0 = 0; k0 < 128; k0 += 32) {
                __syncthreads();   // covers h-write visibility + Wh overwrite
                #pragma unroll
                for (int h = 0; h < 2; ++h) {
                    int r = wrow + h * 64;
                    long wo = (long)(nt * 128 + r) * 128;
                    *(uint4*)(&Wh[r * 40 + wcol]) =
                        *(const uint4*)(pW2h + wo + k0 + wcol);
                    *(uint4*)(&Wl[r * 40 + wcol]) =
                        *(const uint4*)(pW2l + wo + k0 + wcol);
                }
                __syncthreads();
                short8 af[2], alf[2], wf[2], wlf[2];
                #pragma unroll
                for (int i = 0; i < 2; ++i) {
                    af[i]  = *(const short8*)(&Hh[(i * 16 + lr) * 136 + k0 + lk]);
                    alf[i] = *(const short8*)(&Hl[(i * 16 + lr) * 136 + k0 + lk]);
                }
                #pragma unroll
                for (int j = 0; j < 2; ++j) {
                    wf[j]  = *(const short8*)(&Wh[(wn + j * 16 + lr) * 40 + lk]);
                    wlf[j] = *(const short8*)(&Wl[(wn + j * 16 + lr) * 40 + lk]);
                }
                #pragma unroll
                for (int i = 0; i < 2; ++i)
                    #pragma unroll
                    for (int j = 0; j < 2; ++j) {
                        c2[i][j] = __builtin_amdgcn_mfma_f32_16x16x32_bf16(
                            af[i], wf[j], c2[i][j], 0, 0, 0);
                        c2[i][j] = __builtin_amdgcn_mfma_f32_16x16x32_bf16(
                            af[i], wlf[j], c2[i][j], 0, 0, 0);
                        c2[i][j] = __builtin_amdgcn_mfma_f32_16x16x32_bf16(
                            alf[i], wf[j], c2[i][j], 0, 0, 0);
                    }
            }
            #pragma unroll
            for (int i = 0; i < 2; ++i)
                #pragma unroll
                for (int r = 0; r < 4; ++r) {
                    int m = m0 + i * 16 + quad * 4 + r;
                    if (m >= M) continue;
                    #pragma unroll
                    for (int j = 0; j < 2; ++j) {
                        int n = nt * 128 + wn + j * 16 + lr;
                        pout[(long)m * 384 + n] = f2b(c2[i][j][r] + pb2[n]);
                    }
                }
        }
    }
}

// ---------------------------------------------------------------------------
// Fused U+V GEMM over vn in [node][4comp][feat] layout (comp3 = zero).
// Emits uvd = {u0,u1,u2,dot(u,v)} and nrm = |v| directly (R11, proven).
// ---------------------------------------------------------------------------
__global__ __launch_bounds__(256, 2) void gemm_uv_kernel(
    const ushort_t* __restrict__ Ahg, const ushort_t* __restrict__ Alg,
    const ushort_t* __restrict__ Uh, const ushort_t* __restrict__ Ul,
    const ushort_t* __restrict__ Vh, const ushort_t* __restrict__ Vl,
    float4* __restrict__ uvd, float* __restrict__ nrm,
    int Mr)                                     // Mr = 4N rows, K = 128
{
    __shared__ __align__(16) ushort_t Ah[128 * 40];
    __shared__ __align__(16) ushort_t Al[128 * 40];
    __shared__ __align__(16) ushort_t WUh[128 * 40];
    __shared__ __align__(16) ushort_t WUl[128 * 40];
    __shared__ __align__(16) ushort_t WVh[128 * 40];
    __shared__ __align__(16) ushort_t WVl[128 * 40];
    const int t    = threadIdx.x;
    const int m0   = blockIdx.x * 128;
    const int wv   = t >> 6;
    const int lane = t & 63;
    const int wm   = (wv >> 1) * 64;
    const int wn   = (wv & 1) * 64;
    const int lr   = lane & 15;
    const int lk   = (lane >> 4) * 8;
    const int quad = lane >> 4;
    const int srow = t >> 2;
    const int scol = (t & 3) * 8;

    floatx4 aU[4][4] = {};
    floatx4 aV[4][4] = {};

    for (int k0 = 0; k0 < 128; k0 += 32) {
        #pragma unroll
        for (int h = 0; h < 2; ++h) {
            int r = srow + h * 64;
            int m = m0 + r; if (m >= Mr) m = Mr - 1;
            *(uint4*)(&Ah[r * 40 + scol])  = *(const uint4*)(Ahg + (long)m * 128 + k0 + scol);
            *(uint4*)(&Al[r * 40 + scol])  = *(const uint4*)(Alg + (long)m * 128 + k0 + scol);
            *(uint4*)(&WUh[r * 40 + scol]) = *(const uint4*)(Uh + (long)r * 128 + k0 + scol);
            *(uint4*)(&WUl[r * 40 + scol]) = *(const uint4*)(Ul + (long)r * 128 + k0 + scol);
            *(uint4*)(&WVh[r * 40 + scol]) = *(const uint4*)(Vh + (long)r * 128 + k0 + scol);
            *(uint4*)(&WVl[r * 40 + scol]) = *(const uint4*)(Vl + (long)r * 128 + k0 + scol);
        }
        __syncthreads();
        short8 ah[4], al[4];
        #pragma unroll
        for (int i = 0; i < 4; ++i) {
            ah[i] = *(const short8*)(&Ah[(wm + i * 16 + lr) * 40 + lk]);
            al[i] = *(const short8*)(&Al[(wm + i * 16 + lr) * 40 + lk]);
        }
        #pragma unroll
        for (int j = 0; j < 4; ++j) {
            short8 wuh = *(const short8*)(&WUh[(wn + j * 16 + lr) * 40 + lk]);
            short8 wul = *(const short8*)(&WUl[(wn + j * 16 + lr) * 40 + lk]);
            short8 wvh = *(const short8*)(&WVh[(wn + j * 16 + lr) * 40 + lk]);
            short8 wvl = *(const short8*)(&WVl[(wn + j * 16 + lr) * 40 + lk]);
            #pragma unroll
            for (int i = 0; i < 4; ++i) {
                aU[i][j] = __builtin_amdgcn_mfma_f32_16x16x32_bf16(
                    ah[i], wuh, aU[i][j], 0, 0, 0);
                aU[i][j] = __builtin_amdgcn_mfma_f32_16x16x32_bf16(
                    ah[i], wul, aU[i][j], 0, 0, 0);
                aU[i][j] = __builtin_amdgcn_mfma_f32_16x16x32_bf16(
                    al[i], wuh, aU[i][j], 0, 0, 0);
                aV[i][j] = __builtin_amdgcn_mfma_f32_16x16x32_bf16(
                    ah[i], wvh, aV[i][j], 0, 0, 0);
                aV[i][j] = __builtin_amdgcn_mfma_f32_16x16x32_bf16(
                    ah[i], wvl, aV[i][j], 0, 0, 0);
                aV[i][j] = __builtin_amdgcn_mfma_f32_16x16x32_bf16(
                    al[i], wvh, aV[i][j], 0, 0, 0);
            }
        }
        __syncthreads();
    }

    #pragma unroll
    for (int i = 0; i < 4; ++i) {
        int mbase = m0 + wm + i * 16 + quad * 4;   // multiple of 4
        if (mbase >= Mr) continue;
        int node = mbase >> 2;
        #pragma unroll
        for (int j = 0; j < 4; ++j) {
            int n = wn + j * 16 + lr;
            float u0 = aU[i][j][0], u1 = aU[i][j][1], u2 = aU[i][j][2];
            float w0 = aV[i][j][0], w1 = aV[i][j][1], w2 = aV[i][j][2];
            float dot = u0 * w0 + u1 * w1 + u2 * w2;
            uvd[(long)node * 128 + n] = make_float4(u0, u1, u2, dot);
            nrm[(long)node * 128 + n] = sqrtf(w0 * w0 + w1 * w1 + w2 * w2);
        }
    }
}

// ---------------------------------------------------------------------------
__global__ __launch_bounds__(256) void split_kernel(
    const float* __restrict__ src, ushort_t* __restrict__ hi,
    ushort_t* __restrict__ lo, int n)
{
    int i = blockIdx.x * blockDim.x + threadIdx.x;
    if (i >= n) return;
    float x = src[i];
    unsigned short h = f2b(x);
    hi[i] = h;
    lo[i] = f2b(x - b2f(h));
}

// ---------------------------------------------------------------------------
// CSR build
// ---------------------------------------------------------------------------
__global__ __launch_bounds__(256) void hist_kernel(
    const int* __restrict__ nbr, int* __restrict__ deg, int Ed)
{
    int e = blockIdx.x * blockDim.x + threadIdx.x;
    if (e >= Ed) return;
    int E = Ed >> 1;
    int i = (e < E) ? nbr[2 * e] : nbr[2 * (e - E) + 1];
    atomicAdd(&deg[i], 1);
}

__device__ inline int wave_incl_scan(int x, int lane)
{
    #pragma unroll
    for (int s = 1; s < 64; s <<= 1) {
        int y = __shfl_up(x, s, 64);
        if (lane >= s) x += y;
    }
    return x;
}

__global__ __launch_bounds__(1024) void scan_kernel(
    const int* __restrict__ deg, int* __restrict__ off,
    int* __restrict__ cursor, int N)
{
    __shared__ int wsum[16];
    __shared__ int carry_s;
    const int t = threadIdx.x;
    const int lane = t & 63;
    const int w = t >> 6;
    if (t == 0) { carry_s = 0; off[0] = 0; }
    __syncthreads();
    for (int base = 0; base < N; base += 1024) {
        int i = base + t;
        int x = (i < N) ? deg[i] : 0;
        int sc = wave_incl_scan(x, lane);
        if (lane == 63) wsum[w] = sc;
        __syncthreads();
        if (w == 0) {
            int v = (lane < 16) ? wsum[lane] : 0;
            int vs = wave_incl_scan(v, lane);
            if (lane < 16) wsum[lane] = vs;
        }
        __syncthreads();
        int waveoff = (w > 0) ? wsum[w - 1] : 0;
        int inc = sc + waveoff + carry_s;
        if (i < N) { off[i + 1] = inc; cursor[i] = inc - x; }
        __syncthreads();
        if (t == 1023) carry_s = inc;
        __syncthreads();
    }
}

__global__ __launch_bounds__(256) void scatter_geom_kernel(
    const int* __restrict__ nbr, const float* __restrict__ xyz,
    int* __restrict__ cursor, int* __restrict__ csr_j,
    float* __restrict__ csr_env, float* __restrict__ csr_unit,
    float* __restrict__ csr_rbfe, int Ed)
{
    int e = blockIdx.x * blockDim.x + threadIdx.x;
    if (e >= Ed) return;
    int E = Ed >> 1;
    int i, j;
    if (e < E) { i = nbr[2 * e];         j = nbr[2 * e + 1]; }
    else       { int u = e - E; i = nbr[2 * u + 1]; j = nbr[2 * u]; }

    int p = atomicAdd(&cursor[i], 1);
    csr_j[p] = j;

    float rx = xyz[3 * j + 0] - xyz[3 * i + 0];
    float ry = xyz[3 * j + 1] - xyz[3 * i + 1];
    float rz = xyz[3 * j + 2] - xyz[3 * i + 2];
    float d   = sqrtf(rx * rx + ry * ry + rz * rz);
    float inv = 1.f / d;
    csr_unit[3 * p + 0] = rx * inv;
    csr_unit[3 * p + 1] = ry * inv;
    csr_unit[3 * p + 2] = rz * inv;
    float ev = (d < 20.f) ? 0.5f * (__cosf(PI_F * d / 20.f) + 1.f) : 0.f;
    csr_env[p] = ev;
    float base = PI_F * d / 20.f;
    #pragma unroll
    for (int k = 0; k < NRBF; ++k)
        csr_rbfe[(long)p * NRBF + k] = ev * __sinf((float)(k + 1) * base) * inv;
}

// ---------------------------------------------------------------------------
// Edge aggregation — EXACT R0 inner loop, grid 2048 (proven optimum).
// vnh/vnl stores in [node][4comp][feat] layout (comp3 pre-zeroed once).
// ---------------------------------------------------------------------------
__global__ __launch_bounds__(128) void edge_aggr_kernel(
    const int* __restrict__ off, const int* __restrict__ csr_j,
    const float* __restrict__ csr_env, const float* __restrict__ csr_unit,
    const float* __restrict__ csr_rbfe,
    const ushort_t* __restrict__ phib, const float* __restrict__ vold,
    const float* __restrict__ distW, const float* __restrict__ distb,
    float* __restrict__ s, float* __restrict__ vnew,
    ushort_t* __restrict__ vnh, ushort_t* __restrict__ vnl, int N, int SP)
{
    const int f = threadIdx.x;
    float w0c[NRBF], w1c[NRBF], w2c[NRBF];
    const float b0 = distb[f];
    const float b1 = distb[128 + f];
    const float b2 = distb[256 + f];
    #pragma unroll
    for (int k = 0; k < NRBF; ++k) {
        w0c[k] = distW[(long)f * NRBF + k];
        w1c[k] = distW[(long)(128 + f) * NRBF + k];
        w2c[k] = distW[(long)(256 + f) * NRBF + k];
    }

    for (int node = blockIdx.x; node < N; node += gridDim.x) {
        const int p0 = off[node], p1 = off[node + 1];
        float ssum = 0.f, v0 = 0.f, v1 = 0.f, v2 = 0.f;
        for (int p = p0; p < p1; ++p) {
            int j = csr_j[p];
            float ev = csr_env[p];
            float ux = csr_unit[3 * p + 0];
            float uy = csr_unit[3 * p + 1];
            float uz = csr_unit[3 * p + 2];
            const float* rb = csr_rbfe + (long)p * NRBF;
            float w0 = ev * b0, w1 = ev * b1, w2 = ev * b2;
            #pragma unroll
            for (int k = 0; k < NRBF; ++k) {
                float r = rb[k];
                w0 += r * w0c[k];
                w1 += r * w1c[k];
                w2 += r * w2c[k];
            }
            long jb = (long)j * 384;
            float i0 = b2f(phib[jb + f])       * w0;
            float i1 = b2f(phib[jb + 128 + f]) * w1;
            float i2 = b2f(phib[jb + 256 + f]) * w2;
            long jv = (long)j * FEAT + f;
            ssum += i1;
            v0 += i2 * ux + i0 * vold[jv];
            v1 += i2 * uy + i0 * vold[SP + jv];
            v2 += i2 * uz + i0 * vold[2 * SP + jv];
        }
        long iv = (long)node * FEAT + f;
        s[iv] += ssum;
        float n0 = vold[iv]          + v0;
        float n1 = vold[SP + iv]     + v1;
        float n2 = vold[2 * SP + iv] + v2;
        vnew[iv]          = n0;
        vnew[SP + iv]     = n1;
        vnew[2 * SP + iv] = n2;
        unsigned short h0 = f2b(n0), h1 = f2b(n1), h2 = f2b(n2);
        long ib = (long)node * 512 + f;      // [node][4comp][feat] layout
        vnh[ib]       = h0;  vnl[ib]       = f2b(n0 - b2f(h0));
        vnh[ib + 128] = h1;  vnl[ib + 128] = f2b(n1 - b2f(h1));
        vnh[ib + 256] = h2;  vnl[ib + 256] = f2b(n2 - b2f(h2));
    }
}

// ---------------------------------------------------------------------------
// Elementwise kernels
// ---------------------------------------------------------------------------
__global__ __launch_bounds__(256) void init_s_kernel(
    const float* __restrict__ cg_s, float* __restrict__ s,
    float* __restrict__ vA, int nS, int nV)
{
    int idx = blockIdx.x * blockDim.x + threadIdx.x;
    if (idx < nS) s[idx] = cg_s[idx];
    if (idx < nV) vA[idx] = 0.f;
}

// ---------------------------------------------------------------------------
extern "C" void kernel_launch(void* const* d_in, const int* in_sizes, int n_in,
                              void* d_out, int out_size, void* d_ws, size_t ws_size,
                              hipStream_t stream)
{
    const float* xyz     = (const float*)d_in[0];
    const int*   nbr     = (const int*)  d_in[1];
    const float* cg_s    = (const float*)d_in[2];
    const float* msg_W1  = (const float*)d_in[3];
    const float* msg_b1  = (const float*)d_in[4];
    const float* msg_W2  = (const float*)d_in[5];
    const float* msg_b2  = (const float*)d_in[6];
    const float* dist_W  = (const float*)d_in[7];
    const float* dist_b  = (const float*)d_in[8];
    const float* upd_U   = (const float*)d_in[9];
    const float* upd_V   = (const float*)d_in[10];
    const float* upd_sW1 = (const float*)d_in[11];
    const float* upd_sb1 = (const float*)d_in[12];
    const float* upd_sW2 = (const float*)d_in[13];
    const float* upd_sb2 = (const float*)d_in[14];

    const int E  = in_sizes[1] / 2;
    const int Ed = 2 * E;
    const int N  = in_sizes[2] / FEAT;
    const int SP = N * FEAT;

    float* s    = (float*)d_out;
    float* outv = (float*)d_out + (long)SP;

    // workspace carve-up
    float* w = (float*)d_ws;
    size_t off_ = 0;
    auto alloc = [&](size_t nelem) {
        float* p = w + off_;
        off_ += (nelem + 255) & ~(size_t)255;
        return p;
    };
    auto allocb = [&](size_t nelem) {
        return (ushort_t*)alloc((nelem + 1) / 2);
    };
    int*   deg      = (int*)alloc((size_t)N);
    int*   off      = (int*)alloc((size_t)N + 1);
    int*   cursor   = (int*)alloc((size_t)N);
    int*   csr_j    = (int*)alloc((size_t)Ed);
    float* csr_env  = alloc((size_t)Ed);
    float* csr_unit = alloc((size_t)Ed * 3);
    float* csr_rbfe = alloc((size_t)Ed * NRBF);
    float* uvd      = alloc((size_t)4 * SP);   // {u0,u1,u2,dot} per (node,g)
    float* nrm      = alloc((size_t)SP);       // |v_v| per (node,g)
    float* vA       = alloc((size_t)3 * SP);
    float* vB       = alloc((size_t)3 * SP);
    ushort_t* phi_b = allocb((size_t)N * 384);
    ushort_t* vnh   = allocb((size_t)4 * SP);  // [node][4comp][feat], comp3=0
    ushort_t* vnl   = allocb((size_t)4 * SP);
    const int n1 = NCONV * FEAT * FEAT;
    const int n2 = NCONV * 3 * FEAT * FEAT;
    const int n3 = NCONV * FEAT * 2 * FEAT;
    ushort_t* w1h  = allocb((size_t)n1);
    ushort_t* w1l  = allocb((size_t)n1);
    ushort_t* w2h  = allocb((size_t)n2);
    ushort_t* w2l  = allocb((size_t)n2);
    ushort_t* uh   = allocb((size_t)n1);
    ushort_t* ul   = allocb((size_t)n1);
    ushort_t* vh   = allocb((size_t)n1);
    ushort_t* vl   = allocb((size_t)n1);
    ushort_t* sw1h = allocb((size_t)n3);
    ushort_t* sw1l = allocb((size_t)n3);
    ushort_t* sw2h = allocb((size_t)n2);
    ushort_t* sw2l = allocb((size_t)n2);
    (void)ws_size; (void)n_in; (void)out_size;

    // weight split (once per launch)
    split_kernel<<<(n1 + 255) / 256, 256, 0, stream>>>(msg_W1, w1h, w1l, n1);
    split_kernel<<<(n2 + 255) / 256, 256, 0, stream>>>(msg_W2, w2h, w2l, n2);
    split_kernel<<<(n1 + 255) / 256, 256, 0, stream>>>(upd_U, uh, ul, n1);
    split_kernel<<<(n1 + 255) / 256, 256, 0, stream>>>(upd_V, vh, vl, n1);
    split_kernel<<<(n3 + 255) / 256, 256, 0, stream>>>(upd_sW1, sw1h, sw1l, n3);
    split_kernel<<<(n2 + 255) / 256, 256, 0, stream>>>(upd_sW2, sw2h, sw2l, n2);

    // init s <- cg_s, vA <- 0; zero vnh/vnl once (comp3 stays 0 across layers)
    {
        int n = 3 * SP;
        init_s_kernel<<<(n + 255) / 256, 256, 0, stream>>>(cg_s, s, vA, SP, n);
        hipMemsetAsync(vnh, 0, (size_t)4 * SP * sizeof(ushort_t), stream);
        hipMemsetAsync(vnl, 0, (size_t)4 * SP * sizeof(ushort_t), stream);
    }

    // CSR build (once per launch)
    hipMemsetAsync(deg, 0, (size_t)N * sizeof(int), stream);
    hist_kernel<<<(Ed + 255) / 256, 256, 0, stream>>>(nbr, deg, Ed);
    scan_kernel<<<1, 1024, 0, stream>>>(deg, off, cursor, N);
    scatter_geom_kernel<<<(Ed + 255) / 256, 256, 0, stream>>>(
        nbr, xyz, cursor, csr_j, csr_env, csr_unit, csr_rbfe, Ed);

    float* vold = vA;
    float* vnew = vB;
    dim3 gM((N + 31) / 32, 1);
    dim3 gUV((4 * N + 127) / 128, 1);
    int edgeGrid = 2048;
    if (edgeGrid > N) edgeGrid = N;

    for (int l = 0; l < NCONV; ++l) {
        const float* b2  = msg_b2  + (long)l * 3 * FEAT;
        const float* dW  = dist_W  + (long)l * 3 * FEAT * NRBF;
        const float* db  = dist_b  + (long)l * 3 * FEAT;
        const float* sb1 = upd_sb1 + (long)l * FEAT;
        const float* sb2 = upd_sb2 + (long)l * 3 * FEAT;
        const long o1 = (long)l * FEAT * FEAT;
        const long o2 = (long)l * 3 * FEAT * FEAT;
        const long o3 = (long)l * FEAT * 2 * FEAT;

        // phi-MLP for layer 0 only; layers 1,2 get phi from the chained MODE 2
        if (l == 0) {
            const float* b1 = msg_b1;
            mlp_fused_kernel<0><<<gM, 256, 0, stream>>>(
                s, nullptr, w1h, w1l, b1, w2h, w2l, b2,
                phi_b, nullptr, nullptr, nullptr, nullptr,
                nullptr, nullptr, nullptr, nullptr, nullptr, nullptr, nullptr,
                N, FEAT, SP);
        }

        // atomic-free message aggregation (R0 loop, 2048 persistent blocks)
        edge_aggr_kernel<<<edgeGrid, 128, 0, stream>>>(
            off, csr_j, csr_env, csr_unit, csr_rbfe, phi_b, vold,
            dW, db, s, vnew, vnh, vnl, N, SP);

        // fused U+V GEMM -> uvd {u0,u1,u2,dot} + nrm
        gemm_uv_kernel<<<gUV, 256, 0, stream>>>(
            vnh, vnl, uh + o1, ul + o1, vh + o1, vl + o1,
            (float4*)uvd, nrm, 4 * N);

        if (l < NCONV - 1) {
            // gate-MLP + update + CHAINED phi-MLP of layer l+1
            const long o1n = (long)(l + 1) * FEAT * FEAT;
            const long o2n = (long)(l + 1) * 3 * FEAT * FEAT;
            const float* pb1 = msg_b1 + (long)(l + 1) * FEAT;
            const float* pb2 = msg_b2 + (long)(l + 1) * 3 * FEAT;
            mlp_fused_kernel<2><<<gM, 256, 0, stream>>>(
                s, nrm, sw1h + o3, sw1l + o3, sb1, sw2h + o2, sw2l + o2, sb2,
                nullptr, (const float4*)uvd, s, vnew, nullptr,
                w1h + o1n, w1l + o1n, pb1, w2h + o2n, w2l + o2n, pb2, phi_b,
                N, 2 * FEAT, SP);
        } else {
            // final gate-MLP + update; v written interleaved straight to output
            mlp_fused_kernel<1><<<gM, 256, 0, stream>>>(
                s, nrm, sw1h + o3, sw1l + o3, sb1, sw2h + o2, sw2l + o2, sb2,
                nullptr, (const float4*)uvd, s, vnew, outv,
                nullptr, nullptr, nullptr, nullptr, nullptr, nullptr, nullptr,
                N, 2 * FEAT, SP);
        }

        float* tmp = vold; vold = vnew; vnew = tmp;
    }
}